// Round 2
// baseline (612.513 us; speedup 1.0000x reference)
//
#include <hip/hip_runtime.h>

// DefectNet forward, restructured:
//  - knn(p,p,16) once (second knn is rows 4i of the first)
//  - edge_conv -> per-point projections (GEMM) + gather-add-relu-max
//  - graph_attn -> qkv GEMM + wave logits/softmax + gather apply
//  - down stage: v = x4@Wtd[3:] + p@Wtd[0:3] (GEMM+add) + gather-max
//  - tail GEMMs with fused epilogues
// All fp32 this round (correctness baseline); MFMA conversion later.

#define NP 8192
#define NDOWN 2048

typedef unsigned long long u64;

__device__ __forceinline__ bool lexless(float ad, int ai, float bd, int bi) {
  return ad < bd || (ad == bd && ai < bi);
}

// ---------------- prep ----------------
__global__ __launch_bounds__(256) void prep_points_k(const float* __restrict__ pts,
                                                     float4* __restrict__ soa) {
  int i = blockIdx.x * 256 + threadIdx.x;  // exactly 8192
  float x = pts[3 * i], y = pts[3 * i + 1], z = pts[3 * i + 2];
  soa[i] = make_float4(x, y, z, x * x + y * y + z * z);
}

// Wcat2 (64 x 256): [We2[0:64]-We2[64:128] | We2[64:128]]
__global__ __launch_bounds__(256) void prep_wcat_k(const float* __restrict__ We2,
                                                   float* __restrict__ wcat) {
  int t = blockIdx.x * 256 + threadIdx.x;  // 16384
  int r = t >> 8, c = t & 255;
  float v;
  if (c < 128) v = We2[r * 128 + c] - We2[(r + 64) * 128 + c];
  else         v = We2[(r + 64) * 128 + (c - 128)];
  wcat[t] = v;
}

// ---------------- knn ----------------
// 256 blocks x 512 thr; block handles 32 queries (8 waves x 4).
// Exact streaming top-16 kept sorted in lanes 0..15 (lex (d, idx) order).
__global__ __launch_bounds__(512) void knn_k(const float4* __restrict__ soa,
                                             int* __restrict__ idxout) {
  __shared__ float4 sp[2048];
  const int lane = threadIdx.x & 63;
  const int wid = threadIdx.x >> 6;
  for (int qi = 0; qi < 4; ++qi) {
    const int q = blockIdx.x * 32 + wid * 4 + qi;
    const float4 qp = soa[q];
    float td = __int_as_float(0x7f800000);  // +inf
    int ti = 0x7fffffff;
    for (int ch = 0; ch < 4; ++ch) {
      __syncthreads();
      for (int e = threadIdx.x; e < 2048; e += 512) sp[e] = soa[ch * 2048 + e];
      __syncthreads();
      for (int c = 0; c < 32; ++c) {
        const int e = c * 64 + lane;
        const float4 P = sp[e];
        const float dot = qp.x * P.x + qp.y * P.y + qp.z * P.z;
        const float d = qp.w + P.w - 2.0f * dot;  // matches ref formula
        const int gidx = ch * 2048 + e;
        const float Td = __shfl(td, 15);
        const int Ti = __shfl(ti, 15);
        u64 mask = __ballot(lexless(d, gidx, Td, Ti));
        while (mask) {
          const int s = (int)__builtin_ctzll(mask);
          mask &= mask - 1;
          const float cd = __shfl(d, s);
          const int ci = __shfl(gidx, s);
          const int p = __popcll(__ballot(lexless(td, ti, cd, ci)));
          if (p < 16) {
            const float ud = __shfl_up(td, 1);
            const int ui = __shfl_up(ti, 1);
            float ntd = td; int nti = ti;
            if (lane > p && lane < 16) { ntd = ud; nti = ui; }
            if (lane == p) { ntd = cd; nti = ci; }
            td = ntd; ti = nti;
          }
        }
      }
    }
    if (lane < 16) idxout[q * 16 + lane] = ti;
  }
}

// ---------------- edge conv ----------------
// bz1 (8192 x 128): cols 0..63 = p@(Wa-Wb), cols 64..127 = p@Wb  (from We1 6x64)
__global__ __launch_bounds__(256) void proj1_k(const float4* __restrict__ soa,
                                               const float* __restrict__ We1,
                                               float* __restrict__ bz1) {
  int t = blockIdx.x * 256 + threadIdx.x;  // 8192*128
  int i = t >> 7, c = t & 127;
  float4 P = soa[i];
  float v;
  if (c < 64) {
    v = P.x * (We1[c] - We1[192 + c]) + P.y * (We1[64 + c] - We1[256 + c]) +
        P.z * (We1[128 + c] - We1[320 + c]);
  } else {
    int cc = c & 63;
    v = P.x * We1[192 + cc] + P.y * We1[256 + cc] + P.z * We1[320 + cc];
  }
  bz1[t] = v;
}

// x[i][c] = max_n relu((base[i][c] + z[j_n][c]) * s[c] + b[c])
template <int C>
__global__ __launch_bounds__(256) void ec_gm_k(const float* __restrict__ bz,
                                               const int* __restrict__ idx,
                                               const float* __restrict__ s,
                                               const float* __restrict__ b,
                                               float* __restrict__ xout) {
  int t = blockIdx.x * 256 + threadIdx.x;  // NP*C
  int i = t / C, c = t % C;
  float base = bz[(size_t)i * (2 * C) + c];
  float scl = s[c], bia = b[c];
  float acc = 0.f;
#pragma unroll
  for (int n = 0; n < 16; ++n) {
    int j = idx[i * 16 + n];
    float z = bz[(size_t)j * (2 * C) + C + c];
    float h = (base + z) * scl + bia;
    acc = fmaxf(acc, fmaxf(h, 0.f));
  }
  xout[(size_t)i * C + c] = acc;
}

// ---------------- attention ----------------
// qkv row layout: [q(0..C-1) | k(C..2C-1) | v(2C..3C-1)], LD = 3C
template <int C, int LD>
__global__ __launch_bounds__(256) void attn_logits_k(const float* __restrict__ qkv,
                                                     const int* __restrict__ idx,
                                                     float* __restrict__ aout,
                                                     float scale) {
  int i = blockIdx.x * 4 + (threadIdx.x >> 6);
  int lane = threadIdx.x & 63;
  constexpr int D = C / 64;
  const float* qrow = qkv + (size_t)i * LD;
  float qv[D];
#pragma unroll
  for (int d = 0; d < D; ++d) qv[d] = qrow[lane + 64 * d];
  float lg[16];
#pragma unroll
  for (int n = 0; n < 16; ++n) {
    int j = idx[i * 16 + n];
    const float* krow = qkv + (size_t)j * LD + C;
    float ssum = 0.f;
#pragma unroll
    for (int d = 0; d < D; ++d) ssum += qv[d] * krow[lane + 64 * d];
    lg[n] = ssum;
  }
#pragma unroll
  for (int n = 0; n < 16; ++n) {
    float v = lg[n];
    for (int o = 32; o >= 1; o >>= 1) v += __shfl_xor(v, o);
    lg[n] = v * scale;
  }
  float m = lg[0];
#pragma unroll
  for (int n = 1; n < 16; ++n) m = fmaxf(m, lg[n]);
  float ssum = 0.f;
#pragma unroll
  for (int n = 0; n < 16; ++n) { lg[n] = __expf(lg[n] - m); ssum += lg[n]; }
  float inv = 1.f / ssum;
  if (lane == 0) {
#pragma unroll
    for (int n = 0; n < 16; ++n) aout[i * 16 + n] = lg[n] * inv;
  }
}

template <int C, int LD>
__global__ __launch_bounds__(256) void attn_apply_k(const float* __restrict__ qkv,
                                                    const int* __restrict__ idx,
                                                    const float* __restrict__ aw,
                                                    const float* __restrict__ s,
                                                    const float* __restrict__ b,
                                                    float* __restrict__ xout) {
  int t = blockIdx.x * 256 + threadIdx.x;  // NP*C
  int i = t / C, c = t % C;
  float acc = 0.f;
#pragma unroll
  for (int n = 0; n < 16; ++n) {
    int j = idx[i * 16 + n];
    acc += aw[i * 16 + n] * qkv[(size_t)j * LD + 2 * C + c];
  }
  float v = acc * s[c] + b[c];
  xout[(size_t)i * C + c] = fmaxf(v, 0.f);
}

// ---------------- down stage ----------------
__global__ __launch_bounds__(256) void pw_k(const float4* __restrict__ soa,
                                            const float* __restrict__ Wtd,
                                            float* __restrict__ pw) {
  int t = blockIdx.x * 256 + threadIdx.x;  // 8192*512
  int i = t >> 9, c = t & 511;
  float4 P = soa[i];
  pw[t] = P.x * Wtd[c] + P.y * Wtd[512 + c] + P.z * Wtd[1024 + c];
}

__global__ __launch_bounds__(256) void down_gm_k(const float* __restrict__ vbuf,
                                                 const float* __restrict__ pw,
                                                 const int* __restrict__ idx,
                                                 const float* __restrict__ sd,
                                                 const float* __restrict__ bd,
                                                 float* __restrict__ xd) {
  int t = blockIdx.x * 256 + threadIdx.x;  // 2048*512
  int i = t >> 9, c = t & 511;
  int qi = 4 * i;
  float pq = pw[(size_t)qi * 512 + c];
  float scl = sd[c], bia = bd[c];
  float acc = 0.f;
#pragma unroll
  for (int n = 0; n < 16; ++n) {
    int j = idx[qi * 16 + n];
    float h = (vbuf[(size_t)j * 512 + c] - pq) * scl + bia;
    acc = fmaxf(acc, fmaxf(h, 0.f));
  }
  xd[t] = acc;
}

__global__ __launch_bounds__(512) void colsum_k(const float* __restrict__ xd,
                                                float* __restrict__ part) {
  int b = blockIdx.x;           // 16
  int c = threadIdx.x;          // 512
  float s = 0.f;
  for (int r = b * 128; r < (b + 1) * 128; ++r) s += xd[(size_t)r * 512 + c];
  part[b * 512 + c] = s;
}

__global__ __launch_bounds__(256) void gterm_k(const float* __restrict__ part,
                                               const float* __restrict__ Wu2,
                                               const float* __restrict__ su2,
                                               const float* __restrict__ bu2,
                                               float* __restrict__ gterm) {
  __shared__ float gm[512];
  int tid = threadIdx.x;
  for (int c = tid; c < 512; c += 256) {
    float s = 0.f;
#pragma unroll
    for (int b = 0; b < 16; ++b) s += part[b * 512 + c];
    gm[c] = s * (1.f / 2048.f);
  }
  __syncthreads();
  float s = 0.f;
  for (int c = 0; c < 512; ++c) s += gm[c] * Wu2[c * 256 + tid];
  gterm[tid] = s * su2[tid] + bu2[tid];
}

// ---------------- GEMM ----------------
// C(MxN) = A(MxK) @ B(KxN), 64x64 tile, BK=16, 256 thr, 4x4 per thread.
// B selected among {B0,B1,B2} by column block (nsub = per-matrix N; nsub=N for single).
// MODE: 0 plain, 1 +D, 2 relu(acc*s1+b1+s2), 3 relu((acc+b1)*s1+s2)
template <int MODE>
__global__ __launch_bounds__(256) void gemm_k(
    const float* __restrict__ A, const float* __restrict__ B0,
    const float* __restrict__ B1, const float* __restrict__ B2, int nsub,
    float* __restrict__ C, int M, int N, int K, const float* __restrict__ D,
    const float* __restrict__ s1, const float* __restrict__ b1,
    const float* __restrict__ s2) {
  __shared__ __align__(16) float As[16 * 65];
  __shared__ __align__(16) float Bs[16 * 64];
  const int bm = blockIdx.y * 64, bn = blockIdx.x * 64;
  const float* B; int nc0;
  if (bn < nsub)          { B = B0; nc0 = bn; }
  else if (bn < 2 * nsub) { B = B1; nc0 = bn - nsub; }
  else                    { B = B2; nc0 = bn - 2 * nsub; }
  const int tid = threadIdx.x;
  const int tx = tid & 15, ty = tid >> 4;
  const int lm = tid >> 2, lkq = tid & 3;   // A loader
  const int lk = tid >> 4, lnq = tid & 15;  // B loader
  float acc[4][4] = {};
  for (int k0 = 0; k0 < K; k0 += 16) {
    __syncthreads();
    float4 av = *(const float4*)&A[(size_t)(bm + lm) * K + k0 + lkq * 4];
    float4 bv = *(const float4*)&B[(size_t)(k0 + lk) * nsub + nc0 + lnq * 4];
    As[(lkq * 4 + 0) * 65 + lm] = av.x;
    As[(lkq * 4 + 1) * 65 + lm] = av.y;
    As[(lkq * 4 + 2) * 65 + lm] = av.z;
    As[(lkq * 4 + 3) * 65 + lm] = av.w;
    *(float4*)&Bs[lk * 64 + lnq * 4] = bv;
    __syncthreads();
#pragma unroll
    for (int k = 0; k < 16; ++k) {
      float4 b4 = *(const float4*)&Bs[k * 64 + tx * 4];
      float a0 = As[k * 65 + ty * 4 + 0];
      float a1 = As[k * 65 + ty * 4 + 1];
      float a2 = As[k * 65 + ty * 4 + 2];
      float a3 = As[k * 65 + ty * 4 + 3];
      acc[0][0] += a0 * b4.x; acc[0][1] += a0 * b4.y; acc[0][2] += a0 * b4.z; acc[0][3] += a0 * b4.w;
      acc[1][0] += a1 * b4.x; acc[1][1] += a1 * b4.y; acc[1][2] += a1 * b4.z; acc[1][3] += a1 * b4.w;
      acc[2][0] += a2 * b4.x; acc[2][1] += a2 * b4.y; acc[2][2] += a2 * b4.z; acc[2][3] += a2 * b4.w;
      acc[3][0] += a3 * b4.x; acc[3][1] += a3 * b4.y; acc[3][2] += a3 * b4.z; acc[3][3] += a3 * b4.w;
    }
  }
#pragma unroll
  for (int r = 0; r < 4; ++r) {
    int row = bm + ty * 4 + r;
#pragma unroll
    for (int cq = 0; cq < 4; ++cq) {
      int col = bn + tx * 4 + cq;
      float v = acc[r][cq];
      if (MODE == 1) v += D[(size_t)row * N + col];
      if (MODE == 2) v = fmaxf(v * s1[col] + b1[col] + s2[col], 0.f);
      if (MODE == 3) v = fmaxf((v + b1[col]) * s1[col] + s2[col], 0.f);
      C[(size_t)row * N + col] = v;
    }
  }
}

// ---------------- final ----------------
__global__ __launch_bounds__(256) void out_k(const float* __restrict__ h,
                                             const float* __restrict__ Wc2,
                                             const float* __restrict__ bc2,
                                             float* __restrict__ out) {
  int t = blockIdx.x * 256 + threadIdx.x;  // 2048*6 = 12288
  int i = t / 6, o = t % 6;
  float s = bc2[o];
#pragma unroll 8
  for (int m = 0; m < 128; ++m) s += h[i * 128 + m] * Wc2[m * 6 + o];
  out[t] = s;
}

extern "C" void kernel_launch(void* const* d_in, const int* in_sizes, int n_in,
                              void* d_out, int out_size, void* d_ws, size_t ws_size,
                              hipStream_t stream) {
  const float* pts = (const float*)d_in[0];
  const float* We1 = (const float*)d_in[1];
  const float* se1 = (const float*)d_in[2];
  const float* be1 = (const float*)d_in[3];
  const float* We2 = (const float*)d_in[4];
  const float* se2 = (const float*)d_in[5];
  const float* be2 = (const float*)d_in[6];
  const float* Wq1 = (const float*)d_in[7];
  const float* Wk1 = (const float*)d_in[8];
  const float* Wv1 = (const float*)d_in[9];
  const float* sa1 = (const float*)d_in[10];
  const float* ba1 = (const float*)d_in[11];
  const float* Wq2 = (const float*)d_in[12];
  const float* Wk2 = (const float*)d_in[13];
  const float* Wv2 = (const float*)d_in[14];
  const float* sa2 = (const float*)d_in[15];
  const float* ba2 = (const float*)d_in[16];
  const float* Wtd = (const float*)d_in[17];
  const float* sd  = (const float*)d_in[18];
  const float* bd  = (const float*)d_in[19];
  const float* Wu1 = (const float*)d_in[20];
  const float* su1 = (const float*)d_in[21];
  const float* bu1 = (const float*)d_in[22];
  const float* Wu2 = (const float*)d_in[23];
  const float* su2 = (const float*)d_in[24];
  const float* bu2 = (const float*)d_in[25];
  const float* Wc1 = (const float*)d_in[26];
  const float* bc1 = (const float*)d_in[27];
  const float* sc  = (const float*)d_in[28];
  const float* bc  = (const float*)d_in[29];
  const float* Wc2 = (const float*)d_in[30];
  const float* bc2 = (const float*)d_in[31];

  // workspace layout (floats)
  float* ws = (float*)d_ws;
  if (ws_size < (size_t)21299200 * 4) return;  // need ~85.2 MB
  float* soa   = ws;               // 32768  (float4[8192]: x,y,z,|p|^2)
  float* wcat2 = ws + 32768;       // 16384
  int*   idx   = (int*)(ws + 49152);  // 131072 ints
  float* attw  = ws + 180224;      // 131072
  float* gpart = ws + 311296;      // 8192
  float* gterm = ws + 319488;      // 256
  float* pw    = ws + 327680;      // 4194304
  float* bigA  = ws + 4521984;     // 12582912 (48 MB)
  float* bigB  = ws + 17104896;    // 4194304  (16 MB)

  prep_points_k<<<32, 256, 0, stream>>>(pts, (float4*)soa);
  prep_wcat_k<<<64, 256, 0, stream>>>(We2, wcat2);
  knn_k<<<256, 512, 0, stream>>>((const float4*)soa, idx);

  // edge conv 1: bz1 in bigA, x1 (8192x64) in bigB
  proj1_k<<<4096, 256, 0, stream>>>((const float4*)soa, We1, bigA);
  ec_gm_k<64><<<2048, 256, 0, stream>>>(bigA, idx, se1, be1, bigB);

  // edge conv 2: bz2 = x1 @ Wcat2 (8192x256) in bigA, x2 (8192x128) in bigB
  gemm_k<0><<<dim3(4, 128), 256, 0, stream>>>(bigB, wcat2, wcat2, wcat2, 256,
                                              bigA, NP, 256, 64, nullptr, nullptr, nullptr, nullptr);
  ec_gm_k<128><<<4096, 256, 0, stream>>>(bigA, idx, se2, be2, bigB);

  // attn 1: qkv (8192x768) in bigA, x3 (8192x256) in bigB
  gemm_k<0><<<dim3(12, 128), 256, 0, stream>>>(bigB, Wq1, Wk1, Wv1, 256,
                                               bigA, NP, 768, 128, nullptr, nullptr, nullptr, nullptr);
  attn_logits_k<256, 768><<<2048, 256, 0, stream>>>(bigA, idx, attw, 0.0625f);
  attn_apply_k<256, 768><<<8192, 256, 0, stream>>>(bigA, idx, attw, sa1, ba1, bigB);

  // attn 2: qkv (8192x1536) in bigA, x4 (8192x512) in bigB
  gemm_k<0><<<dim3(24, 128), 256, 0, stream>>>(bigB, Wq2, Wk2, Wv2, 512,
                                               bigA, NP, 1536, 256, nullptr, nullptr, nullptr, nullptr);
  attn_logits_k<512, 1536><<<2048, 256, 0, stream>>>(bigA, idx, attw, 0.04419417382415922f);
  attn_apply_k<512, 1536><<<16384, 256, 0, stream>>>(bigA, idx, attw, sa2, ba2, bigB);

  // down: pw = p @ Wtd[0:3]; v = x4 @ Wtd[3:] + pw (8192x512) in bigA; xd (2048x512) in bigB
  pw_k<<<16384, 256, 0, stream>>>((const float4*)soa, Wtd, pw);
  gemm_k<1><<<dim3(8, 128), 256, 0, stream>>>(bigB, Wtd + 3 * 512, Wtd, Wtd, 512,
                                              bigA, NP, 512, 512, pw, nullptr, nullptr, nullptr);
  down_gm_k<<<4096, 256, 0, stream>>>(bigA, pw, idx, sd, bd, bigB);

  // global mean term
  colsum_k<<<16, 512, 0, stream>>>(bigB, gpart);
  gterm_k<<<1, 256, 0, stream>>>(gpart, Wu2, su2, bu2, gterm);

  // xu = relu(xd@Wu1*su1 + bu1 + gterm) (2048x256) in bigA
  gemm_k<2><<<dim3(4, 32), 256, 0, stream>>>(bigB, Wu1, Wu1, Wu1, 256,
                                             bigA, NDOWN, 256, 512, nullptr, su1, bu1, gterm);
  // h = relu((xu@Wc1 + bc1)*sc + bc) (2048x128) in bigB
  gemm_k<3><<<dim3(2, 32), 256, 0, stream>>>(bigA, Wc1, Wc1, Wc1, 128,
                                             bigB, NDOWN, 128, 256, nullptr, sc, bc1, bc);
  // out = h@Wc2 + bc2 (2048x6)
  out_k<<<48, 256, 0, stream>>>(bigB, Wc2, bc2, (float*)d_out);
}

// Round 4
// 415.535 us; speedup vs baseline: 1.4740x; 1.4740x over previous
//
#include <hip/hip_runtime.h>

// DefectNet forward. Round 4:
//  - knn: tau-prefilter with margin + sentinel-escape + exact serial insert
//  - all GEMMs: bf16 MFMA 16x16x32, 3-term hi/lo split (near-fp32 accuracy)
//  - weights transpose-split once per call (wsplit_k)

#define NP 8192
#define NDOWN 2048

typedef unsigned long long u64;
typedef __attribute__((ext_vector_type(8))) short short8;
typedef __attribute__((ext_vector_type(8))) unsigned short ushort8;
typedef __attribute__((ext_vector_type(4))) float f32x4;

__device__ __forceinline__ bool lexless(float ad, int ai, float bd, int bi) {
  return ad < bd || (ad == bd && ai < bi);
}

__device__ __forceinline__ unsigned short f2bf(float x) {
  unsigned u = __float_as_uint(x);
  unsigned r = (u + 0x7fffu + ((u >> 16) & 1u)) >> 16;
  return (unsigned short)r;
}
__device__ __forceinline__ float bf2f(unsigned short h) {
  return __uint_as_float(((unsigned)h) << 16);
}

// ---------------- prep ----------------
__global__ __launch_bounds__(256) void prep_points_k(const float* __restrict__ pts,
                                                     float4* __restrict__ soa) {
  int i = blockIdx.x * 256 + threadIdx.x;  // 8192
  float x = pts[3 * i], y = pts[3 * i + 1], z = pts[3 * i + 2];
  soa[i] = make_float4(x, y, z, x * x + y * y + z * z);
}

// Build all transposed weight planes (bf16 hi/lo), element t in [0, 933888).
// Segments (N x K, row-major in K):
//  S0 [0,16384):      wcat2^T   256x64   (from We2 combine)
//  S1 [16384,114688): wqkv1^T   768x128  (Wq1|Wk1|Wv1)
//  S2 [114688,507904):wqkv2^T  1536x256
//  S3 [507904,770048):wtdx^T    512x512  (Wtd rows 3..514)
//  S4 [770048,901120):wu1^T     256x512
//  S5 [901120,933888):wc1^T     128x256
__global__ __launch_bounds__(256) void wsplit_k(
    const float* __restrict__ We2, const float* __restrict__ Wq1,
    const float* __restrict__ Wk1, const float* __restrict__ Wv1,
    const float* __restrict__ Wq2, const float* __restrict__ Wk2,
    const float* __restrict__ Wv2, const float* __restrict__ Wtd,
    const float* __restrict__ Wu1, const float* __restrict__ Wc1,
    unsigned short* __restrict__ whi, unsigned short* __restrict__ wlo) {
  int t = blockIdx.x * 256 + threadIdx.x;
  float v;
  if (t < 16384) {
    int n = t >> 6, k = t & 63;
    if (n < 128) v = We2[k * 128 + n] - We2[(k + 64) * 128 + n];
    else         v = We2[(k + 64) * 128 + (n - 128)];
  } else if (t < 114688) {
    int e = t - 16384;
    int n = e >> 7, k = e & 127;
    if (n < 256)      v = Wq1[k * 256 + n];
    else if (n < 512) v = Wk1[k * 256 + (n - 256)];
    else              v = Wv1[k * 256 + (n - 512)];
  } else if (t < 507904) {
    int e = t - 114688;
    int n = e >> 8, k = e & 255;
    if (n < 512)       v = Wq2[k * 512 + n];
    else if (n < 1024) v = Wk2[k * 512 + (n - 512)];
    else               v = Wv2[k * 512 + (n - 1024)];
  } else if (t < 770048) {
    int e = t - 507904;
    int n = e >> 9, k = e & 511;
    v = Wtd[(3 + k) * 512 + n];
  } else if (t < 901120) {
    int e = t - 770048;
    int n = e >> 9, k = e & 511;
    v = Wu1[k * 256 + n];
  } else {
    int e = t - 901120;
    int n = e >> 8, k = e & 255;
    v = Wc1[k * 128 + n];
  }
  unsigned short hi = f2bf(v);
  unsigned short lo = f2bf(v - bf2f(hi));
  whi[t] = hi;
  wlo[t] = lo;
}

// ---------------- knn ----------------
// 1024 blocks x 512 thr; wave w handles query blockIdx*8+w.
// Pass A: per-lane min over its 128 candidates -> bitonic sort 64 -> tau.
// Pass B: ballot-filter (d<=tauM || list-not-full), exact serial insert.
// Exactness comes from the lex insert check alone; tau is only a pruner,
// with margin so cross-pass FP contraction differences cannot reject a
// true top-16 member.
__global__ __launch_bounds__(512) void knn_k(const float4* __restrict__ soa,
                                             int* __restrict__ idxout) {
  __shared__ float4 sp[2048];
  const int lane = threadIdx.x & 63;
  const int wid = threadIdx.x >> 6;
  const int q = blockIdx.x * 8 + wid;
  const float4 qp = soa[q];

  // ---- pass A ----
  float mind = __int_as_float(0x7f800000);
  for (int ch = 0; ch < 4; ++ch) {
    __syncthreads();
    for (int j = 0; j < 4; ++j) {
      int e = j * 512 + threadIdx.x;
      sp[e] = soa[ch * 2048 + e];
    }
    __syncthreads();
#pragma unroll 8
    for (int c = 0; c < 32; ++c) {
      const float4 P = sp[c * 64 + lane];
      const float dot = qp.x * P.x + qp.y * P.y + qp.z * P.z;
      const float d = qp.w + P.w - 2.0f * dot;
      mind = fminf(mind, d);
    }
  }
  // bitonic ascending sort of mind over 64 lanes
  float v = mind;
#pragma unroll
  for (int k = 2; k <= 64; k <<= 1) {
#pragma unroll
    for (int j = k >> 1; j >= 1; j >>= 1) {
      float o = __shfl_xor(v, j);
      bool takeMin = (((lane & k) == 0) == ((lane & j) == 0));
      v = takeMin ? fminf(v, o) : fmaxf(v, o);
    }
  }
  const float tau = __shfl(v, 15);
  const float tauM = tau + fabsf(tau) * 1e-5f + 1e-12f;

  // ---- pass B ----
  float td = __int_as_float(0x7f800000);
  int ti = 0x7fffffff;
  for (int ch = 0; ch < 4; ++ch) {
    __syncthreads();
    for (int j = 0; j < 4; ++j) {
      int e = j * 512 + threadIdx.x;
      sp[e] = soa[ch * 2048 + e];
    }
    __syncthreads();
    for (int c = 0; c < 32; ++c) {
      const float4 P = sp[c * 64 + lane];
      const float dot = qp.x * P.x + qp.y * P.y + qp.z * P.z;
      const float d = qp.w + P.w - 2.0f * dot;
      const int gidx = ch * 2048 + c * 64 + lane;
      const float Td = __shfl(td, 15);
      const int Ti = __shfl(ti, 15);
      u64 mask = __ballot(((d <= tauM) || (Ti == 0x7fffffff)) &&
                          lexless(d, gidx, Td, Ti));
      while (mask) {
        const int s = (int)__builtin_ctzll(mask);
        mask &= mask - 1;
        const float cd = __shfl(d, s);
        const int ci = __shfl(gidx, s);
        const int p = __popcll(__ballot(lexless(td, ti, cd, ci)));
        if (p < 16) {
          const float ud = __shfl_up(td, 1);
          const int ui = __shfl_up(ti, 1);
          float ntd = td; int nti = ti;
          if (lane > p && lane < 16) { ntd = ud; nti = ui; }
          if (lane == p) { ntd = cd; nti = ci; }
          td = ntd; ti = nti;
        }
      }
    }
  }
  // defensive mask: any residual sentinel becomes a visible numeric error,
  // not an OOB fault in downstream gathers.
  if (lane < 16) idxout[q * 16 + lane] = ti & 8191;
}

// ---------------- edge conv ----------------
__global__ __launch_bounds__(256) void proj1_k(const float4* __restrict__ soa,
                                               const float* __restrict__ We1,
                                               float* __restrict__ bz1) {
  int t = blockIdx.x * 256 + threadIdx.x;  // 8192*128
  int i = t >> 7, c = t & 127;
  float4 P = soa[i];
  float v;
  if (c < 64) {
    v = P.x * (We1[c] - We1[192 + c]) + P.y * (We1[64 + c] - We1[256 + c]) +
        P.z * (We1[128 + c] - We1[320 + c]);
  } else {
    int cc = c & 63;
    v = P.x * We1[192 + cc] + P.y * We1[256 + cc] + P.z * We1[320 + cc];
  }
  bz1[t] = v;
}

template <int C>
__global__ __launch_bounds__(256) void ec_gm_k(const float* __restrict__ bz,
                                               const int* __restrict__ idx,
                                               const float* __restrict__ s,
                                               const float* __restrict__ b,
                                               float* __restrict__ xout) {
  int t = blockIdx.x * 256 + threadIdx.x;  // NP*C
  int i = t / C, c = t % C;
  float base = bz[(size_t)i * (2 * C) + c];
  float scl = s[c], bia = b[c];
  float acc = 0.f;
#pragma unroll
  for (int n = 0; n < 16; ++n) {
    int j = idx[i * 16 + n];
    float z = bz[(size_t)j * (2 * C) + C + c];
    float h = (base + z) * scl + bia;
    acc = fmaxf(acc, fmaxf(h, 0.f));
  }
  xout[(size_t)i * C + c] = acc;
}

// ---------------- attention ----------------
template <int C, int LD>
__global__ __launch_bounds__(256) void attn_logits_k(const float* __restrict__ qkv,
                                                     const int* __restrict__ idx,
                                                     float* __restrict__ aout,
                                                     float scale) {
  int i = blockIdx.x * 4 + (threadIdx.x >> 6);
  int lane = threadIdx.x & 63;
  constexpr int D = C / 64;
  const float* qrow = qkv + (size_t)i * LD;
  float qv[D];
#pragma unroll
  for (int d = 0; d < D; ++d) qv[d] = qrow[lane + 64 * d];
  float lg[16];
#pragma unroll
  for (int n = 0; n < 16; ++n) {
    int j = idx[i * 16 + n];
    const float* krow = qkv + (size_t)j * LD + C;
    float ssum = 0.f;
#pragma unroll
    for (int d = 0; d < D; ++d) ssum += qv[d] * krow[lane + 64 * d];
    lg[n] = ssum;
  }
#pragma unroll
  for (int n = 0; n < 16; ++n) {
    float vv = lg[n];
    for (int o = 32; o >= 1; o >>= 1) vv += __shfl_xor(vv, o);
    lg[n] = vv * scale;
  }
  float m = lg[0];
#pragma unroll
  for (int n = 1; n < 16; ++n) m = fmaxf(m, lg[n]);
  float ssum = 0.f;
#pragma unroll
  for (int n = 0; n < 16; ++n) { lg[n] = __expf(lg[n] - m); ssum += lg[n]; }
  float inv = 1.f / ssum;
  if (lane == 0) {
#pragma unroll
    for (int n = 0; n < 16; ++n) aout[i * 16 + n] = lg[n] * inv;
  }
}

template <int C, int LD>
__global__ __launch_bounds__(256) void attn_apply_k(const float* __restrict__ qkv,
                                                    const int* __restrict__ idx,
                                                    const float* __restrict__ aw,
                                                    const float* __restrict__ s,
                                                    const float* __restrict__ b,
                                                    float* __restrict__ xout) {
  int t = blockIdx.x * 256 + threadIdx.x;  // NP*C
  int i = t / C, c = t % C;
  float acc = 0.f;
#pragma unroll
  for (int n = 0; n < 16; ++n) {
    int j = idx[i * 16 + n];
    acc += aw[i * 16 + n] * qkv[(size_t)j * LD + 2 * C + c];
  }
  float vv = acc * s[c] + b[c];
  xout[(size_t)i * C + c] = fmaxf(vv, 0.f);
}

// ---------------- down stage ----------------
__global__ __launch_bounds__(256) void pw_k(const float4* __restrict__ soa,
                                            const float* __restrict__ Wtd,
                                            float* __restrict__ pw) {
  int t = blockIdx.x * 256 + threadIdx.x;  // 8192*512
  int i = t >> 9, c = t & 511;
  float4 P = soa[i];
  pw[t] = P.x * Wtd[c] + P.y * Wtd[512 + c] + P.z * Wtd[1024 + c];
}

__global__ __launch_bounds__(256) void down_gm_k(const float* __restrict__ vbuf,
                                                 const float* __restrict__ pw,
                                                 const int* __restrict__ idx,
                                                 const float* __restrict__ sd,
                                                 const float* __restrict__ bd,
                                                 float* __restrict__ xd) {
  int t = blockIdx.x * 256 + threadIdx.x;  // 2048*512
  int i = t >> 9, c = t & 511;
  int qi = 4 * i;
  float pq = pw[(size_t)qi * 512 + c];
  float scl = sd[c], bia = bd[c];
  float acc = 0.f;
#pragma unroll
  for (int n = 0; n < 16; ++n) {
    int j = idx[qi * 16 + n];
    float h = (vbuf[(size_t)j * 512 + c] - pq) * scl + bia;
    acc = fmaxf(acc, fmaxf(h, 0.f));
  }
  xd[t] = acc;
}

__global__ __launch_bounds__(512) void colsum_k(const float* __restrict__ xd,
                                                float* __restrict__ part) {
  int b = blockIdx.x;           // 16
  int c = threadIdx.x;          // 512
  float s = 0.f;
  for (int r = b * 128; r < (b + 1) * 128; ++r) s += xd[(size_t)r * 512 + c];
  part[b * 512 + c] = s;
}

__global__ __launch_bounds__(256) void gterm_k(const float* __restrict__ part,
                                               const float* __restrict__ Wu2,
                                               const float* __restrict__ su2,
                                               const float* __restrict__ bu2,
                                               float* __restrict__ gterm) {
  __shared__ float gm[512];
  int tid = threadIdx.x;
  for (int c = tid; c < 512; c += 256) {
    float s = 0.f;
#pragma unroll
    for (int b = 0; b < 16; ++b) s += part[b * 512 + c];
    gm[c] = s * (1.f / 2048.f);
  }
  __syncthreads();
  float s = 0.f;
  for (int c = 0; c < 512; ++c) s += gm[c] * Wu2[c * 256 + tid];
  gterm[tid] = s * su2[tid] + bu2[tid];
}

// ---------------- MFMA GEMM ----------------
// C(MxN) = A(MxK fp32) @ W (given as WT hi/lo bf16, N x K row-major).
// 128x128 tile, BK=32, 4 waves each 64x64. 3-term split MFMA.
// MODE: 0 plain, 1 +D, 2 relu(acc*s1+b1+s2), 3 relu((acc+b1)*s1+s2)
#define LDSROW 80  // bytes per 32-bf16 row (64B data + 16B pad)
template <int MODE>
__global__ __launch_bounds__(256) void gemm_mfma(
    const float* __restrict__ A, const unsigned short* __restrict__ Bhi,
    const unsigned short* __restrict__ Blo, float* __restrict__ C,
    int M, int N, int K, const float* __restrict__ D,
    const float* __restrict__ s1, const float* __restrict__ b1,
    const float* __restrict__ s2) {
  __shared__ __align__(16) char smem[4 * 128 * LDSROW];
  char* Ahi_s = smem;
  char* Alo_s = smem + 128 * LDSROW;
  char* Bhi_s = smem + 2 * 128 * LDSROW;
  char* Blo_s = smem + 3 * 128 * LDSROW;

  const int tid = threadIdx.x;
  const int lane = tid & 63;
  const int wid = tid >> 6;
  const int wm = wid >> 1, wn = wid & 1;
  const int bm = blockIdx.y * 128, bn = blockIdx.x * 128;
  const int r16 = lane & 15, kb = lane >> 4;

  f32x4 acc[4][4];
#pragma unroll
  for (int a = 0; a < 4; ++a)
#pragma unroll
    for (int b = 0; b < 4; ++b) acc[a][b] = (f32x4)(0.f);

  for (int k0 = 0; k0 < K; k0 += 32) {
    __syncthreads();
    // stage A (128x32 fp32 -> bf16 hi/lo), 4 float4 per thread
#pragma unroll
    for (int qq = 0; qq < 4; ++qq) {
      int idx4 = qq * 256 + tid;
      int row = idx4 >> 3, fq = idx4 & 7;
      float4 av = *(const float4*)&A[(size_t)(bm + row) * K + k0 + fq * 4];
      unsigned short h0 = f2bf(av.x), h1 = f2bf(av.y), h2 = f2bf(av.z), h3 = f2bf(av.w);
      unsigned short l0 = f2bf(av.x - bf2f(h0)), l1 = f2bf(av.y - bf2f(h1));
      unsigned short l2 = f2bf(av.z - bf2f(h2)), l3 = f2bf(av.w - bf2f(h3));
      uint2 hp = make_uint2((unsigned)h0 | ((unsigned)h1 << 16),
                            (unsigned)h2 | ((unsigned)h3 << 16));
      uint2 lp = make_uint2((unsigned)l0 | ((unsigned)l1 << 16),
                            (unsigned)l2 | ((unsigned)l3 << 16));
      *(uint2*)(Ahi_s + row * LDSROW + fq * 8) = hp;
      *(uint2*)(Alo_s + row * LDSROW + fq * 8) = lp;
    }
    // stage B (128 rows x 32 bf16 per plane), 2 chunks per thread per plane
#pragma unroll
    for (int qq = 0; qq < 2; ++qq) {
      int idx8 = qq * 256 + tid;
      int row = idx8 >> 2, sq = idx8 & 3;
      ushort8 bh = *(const ushort8*)&Bhi[(size_t)(bn + row) * K + k0 + sq * 8];
      ushort8 bl = *(const ushort8*)&Blo[(size_t)(bn + row) * K + k0 + sq * 8];
      *(ushort8*)(Bhi_s + row * LDSROW + sq * 16) = bh;
      *(ushort8*)(Blo_s + row * LDSROW + sq * 16) = bl;
    }
    __syncthreads();

    short8 ah[4], al[4];
#pragma unroll
    for (int mi = 0; mi < 4; ++mi) {
      int off = (wm * 64 + mi * 16 + r16) * LDSROW + kb * 16;
      ah[mi] = *(const short8*)(Ahi_s + off);
      al[mi] = *(const short8*)(Alo_s + off);
    }
#pragma unroll
    for (int ni = 0; ni < 4; ++ni) {
      int off = (wn * 64 + ni * 16 + r16) * LDSROW + kb * 16;
      short8 bh = *(const short8*)(Bhi_s + off);
      short8 bl = *(const short8*)(Blo_s + off);
#pragma unroll
      for (int mi = 0; mi < 4; ++mi) {
        acc[mi][ni] = __builtin_amdgcn_mfma_f32_16x16x32_bf16(ah[mi], bh, acc[mi][ni], 0, 0, 0);
        acc[mi][ni] = __builtin_amdgcn_mfma_f32_16x16x32_bf16(ah[mi], bl, acc[mi][ni], 0, 0, 0);
        acc[mi][ni] = __builtin_amdgcn_mfma_f32_16x16x32_bf16(al[mi], bh, acc[mi][ni], 0, 0, 0);
      }
    }
  }

#pragma unroll
  for (int mi = 0; mi < 4; ++mi) {
#pragma unroll
    for (int ni = 0; ni < 4; ++ni) {
      int r0 = bm + wm * 64 + mi * 16 + (lane >> 4) * 4;
      int cc = bn + wn * 64 + ni * 16 + (lane & 15);
#pragma unroll
      for (int j = 0; j < 4; ++j) {
        float vv = acc[mi][ni][j];
        int row = r0 + j;
        if (MODE == 1) vv += D[(size_t)row * N + cc];
        if (MODE == 2) vv = fmaxf(vv * s1[cc] + b1[cc] + s2[cc], 0.f);
        if (MODE == 3) vv = fmaxf((vv + b1[cc]) * s1[cc] + s2[cc], 0.f);
        C[(size_t)row * N + cc] = vv;
      }
    }
  }
}

// ---------------- final ----------------
__global__ __launch_bounds__(256) void out_k(const float* __restrict__ h,
                                             const float* __restrict__ Wc2,
                                             const float* __restrict__ bc2,
                                             float* __restrict__ out) {
  int t = blockIdx.x * 256 + threadIdx.x;  // 2048*6 = 12288
  int i = t / 6, o = t % 6;
  float s = bc2[o];
#pragma unroll 8
  for (int m = 0; m < 128; ++m) s += h[i * 128 + m] * Wc2[m * 6 + o];
  out[t] = s;
}

extern "C" void kernel_launch(void* const* d_in, const int* in_sizes, int n_in,
                              void* d_out, int out_size, void* d_ws, size_t ws_size,
                              hipStream_t stream) {
  const float* pts = (const float*)d_in[0];
  const float* We1 = (const float*)d_in[1];
  const float* se1 = (const float*)d_in[2];
  const float* be1 = (const float*)d_in[3];
  const float* We2 = (const float*)d_in[4];
  const float* se2 = (const float*)d_in[5];
  const float* be2 = (const float*)d_in[6];
  const float* Wq1 = (const float*)d_in[7];
  const float* Wk1 = (const float*)d_in[8];
  const float* Wv1 = (const float*)d_in[9];
  const float* sa1 = (const float*)d_in[10];
  const float* ba1 = (const float*)d_in[11];
  const float* Wq2 = (const float*)d_in[12];
  const float* Wk2 = (const float*)d_in[13];
  const float* Wv2 = (const float*)d_in[14];
  const float* sa2 = (const float*)d_in[15];
  const float* ba2 = (const float*)d_in[16];
  const float* Wtd = (const float*)d_in[17];
  const float* sd  = (const float*)d_in[18];
  const float* bd  = (const float*)d_in[19];
  const float* Wu1 = (const float*)d_in[20];
  const float* su1 = (const float*)d_in[21];
  const float* bu1 = (const float*)d_in[22];
  const float* Wu2 = (const float*)d_in[23];
  const float* su2 = (const float*)d_in[24];
  const float* bu2 = (const float*)d_in[25];
  const float* Wc1 = (const float*)d_in[26];
  const float* bc1 = (const float*)d_in[27];
  const float* sc  = (const float*)d_in[28];
  const float* bc  = (const float*)d_in[29];
  const float* Wc2 = (const float*)d_in[30];
  const float* bc2 = (const float*)d_in[31];

  float* ws = (float*)d_ws;
  if (ws_size < (size_t)18014464 * 4) return;  // ~72.1 MB
  float* soa   = ws;                     // 32768
  int*   idx   = (int*)(ws + 32768);     // 131072 ints
  float* attw  = ws + 163840;            // 131072
  float* gpart = ws + 294912;            // 8192
  float* gterm = ws + 303104;            // 256
  unsigned short* wthi = (unsigned short*)(ws + 303360);  // 933888 ushort
  unsigned short* wtlo = (unsigned short*)(ws + 770304);  // 933888 ushort
  float* bigA  = ws + 1237248;           // 12582912
  float* bigB  = ws + 13820160;          // 4194304
  float* pw    = bigA + 6291456;         // 4194304 (inside bigA tail, free at use time)

  prep_points_k<<<32, 256, 0, stream>>>(pts, (float4*)soa);
  wsplit_k<<<3648, 256, 0, stream>>>(We2, Wq1, Wk1, Wv1, Wq2, Wk2, Wv2, Wtd, Wu1, Wc1, wthi, wtlo);
  knn_k<<<1024, 512, 0, stream>>>((const float4*)soa, idx);

  // edge conv 1
  proj1_k<<<4096, 256, 0, stream>>>((const float4*)soa, We1, bigA);
  ec_gm_k<64><<<2048, 256, 0, stream>>>(bigA, idx, se1, be1, bigB);

  // edge conv 2: bz2 = x1 @ wcat2 (8192x256)
  gemm_mfma<0><<<dim3(2, 64), 256, 0, stream>>>(bigB, wthi, wtlo, bigA,
      NP, 256, 64, nullptr, nullptr, nullptr, nullptr);
  ec_gm_k<128><<<4096, 256, 0, stream>>>(bigA, idx, se2, be2, bigB);

  // attn 1: qkv (8192x768)
  gemm_mfma<0><<<dim3(6, 64), 256, 0, stream>>>(bigB, wthi + 16384, wtlo + 16384, bigA,
      NP, 768, 128, nullptr, nullptr, nullptr, nullptr);
  attn_logits_k<256, 768><<<2048, 256, 0, stream>>>(bigA, idx, attw, 0.0625f);
  attn_apply_k<256, 768><<<8192, 256, 0, stream>>>(bigA, idx, attw, sa1, ba1, bigB);

  // attn 2: qkv (8192x1536)
  gemm_mfma<0><<<dim3(12, 64), 256, 0, stream>>>(bigB, wthi + 114688, wtlo + 114688, bigA,
      NP, 1536, 256, nullptr, nullptr, nullptr, nullptr);
  attn_logits_k<512, 1536><<<2048, 256, 0, stream>>>(bigA, idx, attw, 0.04419417382415922f);
  attn_apply_k<512, 1536><<<16384, 256, 0, stream>>>(bigA, idx, attw, sa2, ba2, bigB);

  // down: v = x4 @ wtdx + pw (8192x512)
  pw_k<<<16384, 256, 0, stream>>>((const float4*)soa, Wtd, pw);
  gemm_mfma<1><<<dim3(4, 64), 256, 0, stream>>>(bigB, wthi + 507904, wtlo + 507904, bigA,
      NP, 512, 512, pw, nullptr, nullptr, nullptr);
  down_gm_k<<<4096, 256, 0, stream>>>(bigA, pw, idx, sd, bd, bigB);

  // global mean term
  colsum_k<<<16, 512, 0, stream>>>(bigB, gpart);
  gterm_k<<<1, 256, 0, stream>>>(gpart, Wu2, su2, bu2, gterm);

  // xu = relu(xd@Wu1*su1 + bu1 + gterm) (2048x256)
  gemm_mfma<2><<<dim3(2, 16), 256, 0, stream>>>(bigB, wthi + 770048, wtlo + 770048, bigA,
      NDOWN, 256, 512, nullptr, su1, bu1, gterm);
  // h = relu((xu@Wc1 + bc1)*sc + bc) (2048x128)
  gemm_mfma<3><<<dim3(1, 16), 256, 0, stream>>>(bigA, wthi + 901120, wtlo + 901120,
      bigB + 2097152, NDOWN, 128, 256, nullptr, sc, bc1, bc);
  // out
  out_k<<<48, 256, 0, stream>>>(bigB + 2097152, Wc2, bc2, (float*)d_out);
}

// Round 5
// 391.201 us; speedup vs baseline: 1.5657x; 1.0622x over previous
//
#include <hip/hip_runtime.h>

// DefectNet forward. Round 5:
//  - knn: cached-Td/Ti pass B (no per-iter shfl), tau-prefilter + exact insert
//  - activations stored as bf16 hi/lo planes by producers; GEMM stages both
//    operands as pure ushort8 copies (no conversion VALU in GEMM)
//  - pw folded into down-GEMM epilogue / down_gm (buffer deleted)
//  - gather kernels vectorized float4

#define NP 8192
#define NDOWN 2048

typedef unsigned long long u64;
typedef __attribute__((ext_vector_type(8))) short short8;
typedef __attribute__((ext_vector_type(8))) unsigned short ushort8;
typedef __attribute__((ext_vector_type(4))) float f32x4;

__device__ __forceinline__ bool lexless(float ad, int ai, float bd, int bi) {
  return ad < bd || (ad == bd && ai < bi);
}

__device__ __forceinline__ unsigned short f2bf(float x) {
  unsigned u = __float_as_uint(x);
  unsigned r = (u + 0x7fffu + ((u >> 16) & 1u)) >> 16;
  return (unsigned short)r;
}
__device__ __forceinline__ float bf2f(unsigned short h) {
  return __uint_as_float(((unsigned)h) << 16);
}
__device__ __forceinline__ uint2 pack4h(float a, float b, float c, float d,
                                        unsigned short* l0, unsigned short* l1,
                                        unsigned short* l2, unsigned short* l3) {
  unsigned short h0 = f2bf(a), h1 = f2bf(b), h2 = f2bf(c), h3 = f2bf(d);
  *l0 = f2bf(a - bf2f(h0)); *l1 = f2bf(b - bf2f(h1));
  *l2 = f2bf(c - bf2f(h2)); *l3 = f2bf(d - bf2f(h3));
  return make_uint2((unsigned)h0 | ((unsigned)h1 << 16),
                    (unsigned)h2 | ((unsigned)h3 << 16));
}

// ---------------- prep ----------------
__global__ __launch_bounds__(256) void prep_points_k(const float* __restrict__ pts,
                                                     float4* __restrict__ soa) {
  int i = blockIdx.x * 256 + threadIdx.x;  // 8192
  float x = pts[3 * i], y = pts[3 * i + 1], z = pts[3 * i + 2];
  soa[i] = make_float4(x, y, z, x * x + y * y + z * z);
}

// Transposed weight planes (bf16 hi/lo), t in [0, 933888). Layout as round 4.
__global__ __launch_bounds__(256) void wsplit_k(
    const float* __restrict__ We2, const float* __restrict__ Wq1,
    const float* __restrict__ Wk1, const float* __restrict__ Wv1,
    const float* __restrict__ Wq2, const float* __restrict__ Wk2,
    const float* __restrict__ Wv2, const float* __restrict__ Wtd,
    const float* __restrict__ Wu1, const float* __restrict__ Wc1,
    unsigned short* __restrict__ whi, unsigned short* __restrict__ wlo) {
  int t = blockIdx.x * 256 + threadIdx.x;
  float v;
  if (t < 16384) {
    int n = t >> 6, k = t & 63;
    if (n < 128) v = We2[k * 128 + n] - We2[(k + 64) * 128 + n];
    else         v = We2[(k + 64) * 128 + (n - 128)];
  } else if (t < 114688) {
    int e = t - 16384;
    int n = e >> 7, k = e & 127;
    if (n < 256)      v = Wq1[k * 256 + n];
    else if (n < 512) v = Wk1[k * 256 + (n - 256)];
    else              v = Wv1[k * 256 + (n - 512)];
  } else if (t < 507904) {
    int e = t - 114688;
    int n = e >> 8, k = e & 255;
    if (n < 512)       v = Wq2[k * 512 + n];
    else if (n < 1024) v = Wk2[k * 512 + (n - 512)];
    else               v = Wv2[k * 512 + (n - 1024)];
  } else if (t < 770048) {
    int e = t - 507904;
    int n = e >> 9, k = e & 511;
    v = Wtd[(3 + k) * 512 + n];
  } else if (t < 901120) {
    int e = t - 770048;
    int n = e >> 9, k = e & 511;
    v = Wu1[k * 256 + n];
  } else {
    int e = t - 901120;
    int n = e >> 8, k = e & 255;
    v = Wc1[k * 128 + n];
  }
  unsigned short hi = f2bf(v);
  unsigned short lo = f2bf(v - bf2f(hi));
  whi[t] = hi;
  wlo[t] = lo;
}

// ---------------- knn ----------------
// Pass A: per-lane min -> bitonic-64 -> tau. Pass B: cached Td/Ti filter +
// exact serial insert (stale cache only over-admits; p<16 check is exact).
__global__ __launch_bounds__(512) void knn_k(const float4* __restrict__ soa,
                                             int* __restrict__ idxout) {
  __shared__ float4 sp[2048];
  const int lane = threadIdx.x & 63;
  const int wid = threadIdx.x >> 6;
  const int q = blockIdx.x * 8 + wid;
  const float4 qp = soa[q];

  // ---- pass A ----
  float mind = __int_as_float(0x7f800000);
  for (int ch = 0; ch < 4; ++ch) {
    __syncthreads();
    for (int j = 0; j < 4; ++j) {
      int e = j * 512 + threadIdx.x;
      sp[e] = soa[ch * 2048 + e];
    }
    __syncthreads();
#pragma unroll 8
    for (int c = 0; c < 32; ++c) {
      const float4 P = sp[c * 64 + lane];
      const float dot = qp.x * P.x + qp.y * P.y + qp.z * P.z;
      const float d = qp.w + P.w - 2.0f * dot;
      mind = fminf(mind, d);
    }
  }
  float v = mind;
#pragma unroll
  for (int k = 2; k <= 64; k <<= 1) {
#pragma unroll
    for (int j = k >> 1; j >= 1; j >>= 1) {
      float o = __shfl_xor(v, j);
      bool takeMin = (((lane & k) == 0) == ((lane & j) == 0));
      v = takeMin ? fminf(v, o) : fmaxf(v, o);
    }
  }
  const float tau = __shfl(v, 15);
  const float tauM = tau + fabsf(tau) * 1e-5f + 1e-12f;

  // ---- pass B ----
  float td = __int_as_float(0x7f800000);
  int ti = 0x7fffffff;
  float Td = __int_as_float(0x7f800000);
  int Ti = 0x7fffffff;
  for (int ch = 0; ch < 4; ++ch) {
    __syncthreads();
    for (int j = 0; j < 4; ++j) {
      int e = j * 512 + threadIdx.x;
      sp[e] = soa[ch * 2048 + e];
    }
    __syncthreads();
    for (int c = 0; c < 32; ++c) {
      const float4 P = sp[c * 64 + lane];
      const float dot = qp.x * P.x + qp.y * P.y + qp.z * P.z;
      const float d = qp.w + P.w - 2.0f * dot;
      const int gidx = ch * 2048 + c * 64 + lane;
      bool pass = (d <= tauM) || (Ti == 0x7fffffff);
      u64 mask = __ballot(pass && lexless(d, gidx, Td, Ti));
      if (mask) {
        do {
          const int s = (int)__builtin_ctzll(mask);
          mask &= mask - 1;
          const float cd = __shfl(d, s);
          const int ci = __shfl(gidx, s);
          const int p = __popcll(__ballot(lexless(td, ti, cd, ci)));
          if (p < 16) {
            const float ud = __shfl_up(td, 1);
            const int ui = __shfl_up(ti, 1);
            float ntd = td; int nti = ti;
            if (lane > p && lane < 16) { ntd = ud; nti = ui; }
            if (lane == p) { ntd = cd; nti = ci; }
            td = ntd; ti = nti;
          }
        } while (mask);
        Td = __shfl(td, 15);
        Ti = __shfl(ti, 15);
      }
    }
  }
  if (lane < 16) idxout[q * 16 + lane] = ti & 8191;
}

// ---------------- edge conv ----------------
__global__ __launch_bounds__(256) void proj1_k(const float4* __restrict__ soa,
                                               const float* __restrict__ We1,
                                               float* __restrict__ bz1) {
  int t = blockIdx.x * 256 + threadIdx.x;  // 8192*128
  int i = t >> 7, c = t & 127;
  float4 P = soa[i];
  float v;
  if (c < 64) {
    v = P.x * (We1[c] - We1[192 + c]) + P.y * (We1[64 + c] - We1[256 + c]) +
        P.z * (We1[128 + c] - We1[320 + c]);
  } else {
    int cc = c & 63;
    v = P.x * We1[192 + cc] + P.y * We1[256 + cc] + P.z * We1[320 + cc];
  }
  bz1[t] = v;
}

// x[i][c] = max_n relu((base[i][c] + z[j][c]) * s + b); split bf16 output.
template <int C>
__global__ __launch_bounds__(256) void ec_gm_k(const float* __restrict__ bz,
                                               const int* __restrict__ idx,
                                               const float* __restrict__ s,
                                               const float* __restrict__ b,
                                               unsigned short* __restrict__ xhi,
                                               unsigned short* __restrict__ xlo) {
  constexpr int C4 = C / 4;
  int t = blockIdx.x * 256 + threadIdx.x;  // NP*C4
  int i = t / C4, q = t % C4;
  float4 base = *(const float4*)&bz[(size_t)i * (2 * C) + q * 4];
  float4 scl = *(const float4*)&s[q * 4];
  float4 bia = *(const float4*)&b[q * 4];
  float ax = 0.f, ay = 0.f, az = 0.f, aw = 0.f;
  const int* ip = idx + i * 16;
#pragma unroll
  for (int n = 0; n < 16; ++n) {
    int j = ip[n];
    float4 z = *(const float4*)&bz[(size_t)j * (2 * C) + C + q * 4];
    ax = fmaxf(ax, (base.x + z.x) * scl.x + bia.x);
    ay = fmaxf(ay, (base.y + z.y) * scl.y + bia.y);
    az = fmaxf(az, (base.z + z.z) * scl.z + bia.z);
    aw = fmaxf(aw, (base.w + z.w) * scl.w + bia.w);
  }
  unsigned short l0, l1, l2, l3;
  uint2 hp = pack4h(ax, ay, az, aw, &l0, &l1, &l2, &l3);
  uint2 lp = make_uint2((unsigned)l0 | ((unsigned)l1 << 16),
                        (unsigned)l2 | ((unsigned)l3 << 16));
  *(uint2*)&xhi[(size_t)i * C + q * 4] = hp;
  *(uint2*)&xlo[(size_t)i * C + q * 4] = lp;
}

// ---------------- attention ----------------
template <int C, int LD>
__global__ __launch_bounds__(256) void attn_logits_k(const float* __restrict__ qkv,
                                                     const int* __restrict__ idx,
                                                     float* __restrict__ aout,
                                                     float scale) {
  int i = blockIdx.x * 4 + (threadIdx.x >> 6);
  int lane = threadIdx.x & 63;
  constexpr int D = C / 64;
  const float* qrow = qkv + (size_t)i * LD;
  float qv[D];
#pragma unroll
  for (int d = 0; d < D; ++d) qv[d] = qrow[lane + 64 * d];
  float lg[16];
#pragma unroll
  for (int n = 0; n < 16; ++n) {
    int j = idx[i * 16 + n];
    const float* krow = qkv + (size_t)j * LD + C;
    float ssum = 0.f;
#pragma unroll
    for (int d = 0; d < D; ++d) ssum += qv[d] * krow[lane + 64 * d];
    lg[n] = ssum;
  }
#pragma unroll
  for (int n = 0; n < 16; ++n) {
    float vv = lg[n];
    for (int o = 32; o >= 1; o >>= 1) vv += __shfl_xor(vv, o);
    lg[n] = vv * scale;
  }
  float m = lg[0];
#pragma unroll
  for (int n = 1; n < 16; ++n) m = fmaxf(m, lg[n]);
  float ssum = 0.f;
#pragma unroll
  for (int n = 0; n < 16; ++n) { lg[n] = __expf(lg[n] - m); ssum += lg[n]; }
  float inv = 1.f / ssum;
  if (lane == 0) {
#pragma unroll
    for (int n = 0; n < 16; ++n) aout[i * 16 + n] = lg[n] * inv;
  }
}

template <int C, int LD>
__global__ __launch_bounds__(256) void attn_apply_k(const float* __restrict__ qkv,
                                                    const int* __restrict__ idx,
                                                    const float* __restrict__ aw,
                                                    const float* __restrict__ s,
                                                    const float* __restrict__ b,
                                                    unsigned short* __restrict__ xhi,
                                                    unsigned short* __restrict__ xlo) {
  constexpr int C4 = C / 4;
  int t = blockIdx.x * 256 + threadIdx.x;  // NP*C4
  int i = t / C4, q = t % C4;
  float ax = 0.f, ay = 0.f, az = 0.f, az2 = 0.f;
  const int* ip = idx + i * 16;
  const float* ap = aw + i * 16;
#pragma unroll
  for (int n = 0; n < 16; ++n) {
    int j = ip[n];
    float w = ap[n];
    float4 v = *(const float4*)&qkv[(size_t)j * LD + 2 * C + q * 4];
    ax += w * v.x; ay += w * v.y; az += w * v.z; az2 += w * v.w;
  }
  float4 scl = *(const float4*)&s[q * 4];
  float4 bia = *(const float4*)&b[q * 4];
  ax = fmaxf(ax * scl.x + bia.x, 0.f);
  ay = fmaxf(ay * scl.y + bia.y, 0.f);
  az = fmaxf(az * scl.z + bia.z, 0.f);
  az2 = fmaxf(az2 * scl.w + bia.w, 0.f);
  unsigned short l0, l1, l2, l3;
  uint2 hp = pack4h(ax, ay, az, az2, &l0, &l1, &l2, &l3);
  uint2 lp = make_uint2((unsigned)l0 | ((unsigned)l1 << 16),
                        (unsigned)l2 | ((unsigned)l3 << 16));
  *(uint2*)&xhi[(size_t)i * C + q * 4] = hp;
  *(uint2*)&xlo[(size_t)i * C + q * 4] = lp;
}

// ---------------- down stage ----------------
// xd[i][c] = max_n relu((v[j][c] - pw[4i][c]) * sd + bd); pw recomputed.
__global__ __launch_bounds__(256) void down_gm_k(const float* __restrict__ vbuf,
                                                 const float4* __restrict__ soa,
                                                 const float* __restrict__ Wtd,
                                                 const int* __restrict__ idx,
                                                 const float* __restrict__ sd,
                                                 const float* __restrict__ bd,
                                                 unsigned short* __restrict__ xdhi,
                                                 unsigned short* __restrict__ xdlo) {
  int t = blockIdx.x * 256 + threadIdx.x;  // 2048*128
  int i = t >> 7, q = t & 127;
  int qi = 4 * i;
  float4 qp = soa[qi];
  float4 w0 = *(const float4*)&Wtd[q * 4];
  float4 w1 = *(const float4*)&Wtd[512 + q * 4];
  float4 w2 = *(const float4*)&Wtd[1024 + q * 4];
  float px = qp.x * w0.x + qp.y * w1.x + qp.z * w2.x;
  float py = qp.x * w0.y + qp.y * w1.y + qp.z * w2.y;
  float pz = qp.x * w0.z + qp.y * w1.z + qp.z * w2.z;
  float pw2 = qp.x * w0.w + qp.y * w1.w + qp.z * w2.w;
  float4 scl = *(const float4*)&sd[q * 4];
  float4 bia = *(const float4*)&bd[q * 4];
  float ax = 0.f, ay = 0.f, az = 0.f, aw = 0.f;
  const int* ip = idx + qi * 16;
#pragma unroll
  for (int n = 0; n < 16; ++n) {
    int j = ip[n];
    float4 v = *(const float4*)&vbuf[(size_t)j * 512 + q * 4];
    ax = fmaxf(ax, (v.x - px) * scl.x + bia.x);
    ay = fmaxf(ay, (v.y - py) * scl.y + bia.y);
    az = fmaxf(az, (v.z - pz) * scl.z + bia.z);
    aw = fmaxf(aw, (v.w - pw2) * scl.w + bia.w);
  }
  unsigned short l0, l1, l2, l3;
  uint2 hp = pack4h(ax, ay, az, aw, &l0, &l1, &l2, &l3);
  uint2 lp = make_uint2((unsigned)l0 | ((unsigned)l1 << 16),
                        (unsigned)l2 | ((unsigned)l3 << 16));
  *(uint2*)&xdhi[(size_t)i * 512 + q * 4] = hp;
  *(uint2*)&xdlo[(size_t)i * 512 + q * 4] = lp;
}

__global__ __launch_bounds__(512) void colsum_k(const unsigned short* __restrict__ xdhi,
                                                const unsigned short* __restrict__ xdlo,
                                                float* __restrict__ part) {
  int b = blockIdx.x;           // 16
  int c = threadIdx.x;          // 512
  float s = 0.f;
  for (int r = b * 128; r < (b + 1) * 128; ++r)
    s += bf2f(xdhi[(size_t)r * 512 + c]) + bf2f(xdlo[(size_t)r * 512 + c]);
  part[b * 512 + c] = s;
}

__global__ __launch_bounds__(256) void gterm_k(const float* __restrict__ part,
                                               const float* __restrict__ Wu2,
                                               const float* __restrict__ su2,
                                               const float* __restrict__ bu2,
                                               float* __restrict__ gterm) {
  __shared__ float gm[512];
  int tid = threadIdx.x;
  for (int c = tid; c < 512; c += 256) {
    float s = 0.f;
#pragma unroll
    for (int b = 0; b < 16; ++b) s += part[b * 512 + c];
    gm[c] = s * (1.f / 2048.f);
  }
  __syncthreads();
  float s = 0.f;
  for (int c = 0; c < 512; ++c) s += gm[c] * Wu2[c * 256 + tid];
  gterm[tid] = s * su2[tid] + bu2[tid];
}

// ---------------- MFMA GEMM ----------------
// C = A @ W^T; A given as hi/lo bf16 planes (M x K), W^T as hi/lo (N x K).
// 128x128 tile, BK=32, 4 waves. 3-term split.
// MODE: 0 plain fp32 out; 1 += p@Wtd[0:3] (soa+wtd) fp32 out;
//       2 relu(acc*s1+b1+s2) split out; 3 relu((acc+b1)*s1+s2) fp32 out.
#define LDSROW 80
template <int MODE>
__global__ __launch_bounds__(256) void gemm_mfma(
    const unsigned short* __restrict__ Ahi, const unsigned short* __restrict__ Alo,
    const unsigned short* __restrict__ Bhi, const unsigned short* __restrict__ Blo,
    float* __restrict__ Cf, unsigned short* __restrict__ Chi,
    unsigned short* __restrict__ Clo, int M, int N, int K,
    const float4* __restrict__ soaD, const float* __restrict__ wtd,
    const float* __restrict__ s1, const float* __restrict__ b1,
    const float* __restrict__ s2) {
  __shared__ __align__(16) char smem[4 * 128 * LDSROW];
  char* Ahi_s = smem;
  char* Alo_s = smem + 128 * LDSROW;
  char* Bhi_s = smem + 2 * 128 * LDSROW;
  char* Blo_s = smem + 3 * 128 * LDSROW;

  const int tid = threadIdx.x;
  const int lane = tid & 63;
  const int wid = tid >> 6;
  const int wm = wid >> 1, wn = wid & 1;
  const int bm = blockIdx.y * 128, bn = blockIdx.x * 128;
  const int r16 = lane & 15, kb = lane >> 4;

  f32x4 acc[4][4];
#pragma unroll
  for (int a = 0; a < 4; ++a)
#pragma unroll
    for (int b = 0; b < 4; ++b) acc[a][b] = (f32x4)(0.f);

  for (int k0 = 0; k0 < K; k0 += 32) {
    __syncthreads();
#pragma unroll
    for (int qq = 0; qq < 2; ++qq) {
      int idx8 = qq * 256 + tid;
      int row = idx8 >> 2, sq = idx8 & 3;
      size_t goA = (size_t)(bm + row) * K + k0 + sq * 8;
      size_t goB = (size_t)(bn + row) * K + k0 + sq * 8;
      ushort8 a_h = *(const ushort8*)&Ahi[goA];
      ushort8 a_l = *(const ushort8*)&Alo[goA];
      ushort8 b_h = *(const ushort8*)&Bhi[goB];
      ushort8 b_l = *(const ushort8*)&Blo[goB];
      *(ushort8*)(Ahi_s + row * LDSROW + sq * 16) = a_h;
      *(ushort8*)(Alo_s + row * LDSROW + sq * 16) = a_l;
      *(ushort8*)(Bhi_s + row * LDSROW + sq * 16) = b_h;
      *(ushort8*)(Blo_s + row * LDSROW + sq * 16) = b_l;
    }
    __syncthreads();

    short8 ah[4], al[4];
#pragma unroll
    for (int mi = 0; mi < 4; ++mi) {
      int off = (wm * 64 + mi * 16 + r16) * LDSROW + kb * 16;
      ah[mi] = *(const short8*)(Ahi_s + off);
      al[mi] = *(const short8*)(Alo_s + off);
    }
#pragma unroll
    for (int ni = 0; ni < 4; ++ni) {
      int off = (wn * 64 + ni * 16 + r16) * LDSROW + kb * 16;
      short8 bh = *(const short8*)(Bhi_s + off);
      short8 bl = *(const short8*)(Blo_s + off);
#pragma unroll
      for (int mi = 0; mi < 4; ++mi) {
        acc[mi][ni] = __builtin_amdgcn_mfma_f32_16x16x32_bf16(ah[mi], bh, acc[mi][ni], 0, 0, 0);
        acc[mi][ni] = __builtin_amdgcn_mfma_f32_16x16x32_bf16(ah[mi], bl, acc[mi][ni], 0, 0, 0);
        acc[mi][ni] = __builtin_amdgcn_mfma_f32_16x16x32_bf16(al[mi], bh, acc[mi][ni], 0, 0, 0);
      }
    }
  }

#pragma unroll
  for (int mi = 0; mi < 4; ++mi) {
#pragma unroll
    for (int ni = 0; ni < 4; ++ni) {
      int r0 = bm + wm * 64 + mi * 16 + (lane >> 4) * 4;
      int cc = bn + wn * 64 + ni * 16 + (lane & 15);
      float w0 = 0.f, w1 = 0.f, w2 = 0.f;
      if (MODE == 1) { w0 = wtd[cc]; w1 = wtd[512 + cc]; w2 = wtd[1024 + cc]; }
#pragma unroll
      for (int j = 0; j < 4; ++j) {
        float vv = acc[mi][ni][j];
        int row = r0 + j;
        if (MODE == 1) {
          float4 P = soaD[row];
          vv += P.x * w0 + P.y * w1 + P.z * w2;
        }
        if (MODE == 2) vv = fmaxf(vv * s1[cc] + b1[cc] + s2[cc], 0.f);
        if (MODE == 3) vv = fmaxf((vv + b1[cc]) * s1[cc] + s2[cc], 0.f);
        if (MODE == 2) {
          unsigned short hi = f2bf(vv);
          unsigned short lo = f2bf(vv - bf2f(hi));
          Chi[(size_t)row * N + cc] = hi;
          Clo[(size_t)row * N + cc] = lo;
        } else {
          Cf[(size_t)row * N + cc] = vv;
        }
      }
    }
  }
}

// ---------------- final ----------------
__global__ __launch_bounds__(256) void out_k(const float* __restrict__ h,
                                             const float* __restrict__ Wc2,
                                             const float* __restrict__ bc2,
                                             float* __restrict__ out) {
  int t = blockIdx.x * 256 + threadIdx.x;  // 2048*6 = 12288
  int i = t / 6, o = t % 6;
  float s = bc2[o];
#pragma unroll 8
  for (int m = 0; m < 128; ++m) s += h[i * 128 + m] * Wc2[m * 6 + o];
  out[t] = s;
}

extern "C" void kernel_launch(void* const* d_in, const int* in_sizes, int n_in,
                              void* d_out, int out_size, void* d_ws, size_t ws_size,
                              hipStream_t stream) {
  const float* pts = (const float*)d_in[0];
  const float* We1 = (const float*)d_in[1];
  const float* se1 = (const float*)d_in[2];
  const float* be1 = (const float*)d_in[3];
  const float* We2 = (const float*)d_in[4];
  const float* se2 = (const float*)d_in[5];
  const float* be2 = (const float*)d_in[6];
  const float* Wq1 = (const float*)d_in[7];
  const float* Wk1 = (const float*)d_in[8];
  const float* Wv1 = (const float*)d_in[9];
  const float* sa1 = (const float*)d_in[10];
  const float* ba1 = (const float*)d_in[11];
  const float* Wq2 = (const float*)d_in[12];
  const float* Wk2 = (const float*)d_in[13];
  const float* Wv2 = (const float*)d_in[14];
  const float* sa2 = (const float*)d_in[15];
  const float* ba2 = (const float*)d_in[16];
  const float* Wtd = (const float*)d_in[17];
  const float* sd  = (const float*)d_in[18];
  const float* bd  = (const float*)d_in[19];
  const float* Wu1 = (const float*)d_in[20];
  const float* su1 = (const float*)d_in[21];
  const float* bu1 = (const float*)d_in[22];
  const float* Wu2 = (const float*)d_in[23];
  const float* su2 = (const float*)d_in[24];
  const float* bu2 = (const float*)d_in[25];
  const float* Wc1 = (const float*)d_in[26];
  const float* bc1 = (const float*)d_in[27];
  const float* sc  = (const float*)d_in[28];
  const float* bc  = (const float*)d_in[29];
  const float* Wc2 = (const float*)d_in[30];
  const float* bc2 = (const float*)d_in[31];

  float* ws = (float*)d_ws;
  if (ws_size < (size_t)19587328 * 4) return;  // ~78.3 MB
  float* soa   = ws;                     // 32768
  int*   idx   = (int*)(ws + 32768);     // 131072 ints
  float* attw  = ws + 163840;            // 131072
  float* gpart = ws + 294912;            // 8192
  float* gterm = ws + 303104;            // 256
  unsigned short* wthi = (unsigned short*)(ws + 303360);   // 933888 ush
  unsigned short* wtlo = (unsigned short*)(ws + 770304);   // 933888 ush
  unsigned short* xar  = (unsigned short*)(ws + 1237248);  // 8388608 ush arena
  unsigned short* xdhi = (unsigned short*)(ws + 5431552);  // 1048576 ush
  unsigned short* xdlo = (unsigned short*)(ws + 5955840);  // 1048576 ush
  unsigned short* xuhi = (unsigned short*)(ws + 6480128);  // 524288 ush
  unsigned short* xulo = (unsigned short*)(ws + 6742272);  // 524288 ush
  float* bigA  = ws + 7004416;           // 12582912 floats
  float* hbuf  = bigA + 4194304;         // 262144 floats (reuses dead qkv2 tail)

  prep_points_k<<<32, 256, 0, stream>>>(pts, (float4*)soa);
  wsplit_k<<<3648, 256, 0, stream>>>(We2, Wq1, Wk1, Wv1, Wq2, Wk2, Wv2, Wtd, Wu1, Wc1, wthi, wtlo);
  knn_k<<<1024, 512, 0, stream>>>((const float4*)soa, idx);

  // edge conv 1: bz1 fp32 in bigA; x1 split (8192x64) in arena
  proj1_k<<<4096, 256, 0, stream>>>((const float4*)soa, We1, bigA);
  ec_gm_k<64><<<512, 256, 0, stream>>>(bigA, idx, se1, be1, xar, xar + 524288);

  // edge conv 2: bz2 = x1 @ wcat2 (8192x256 fp32 in bigA); x2 split in arena
  gemm_mfma<0><<<dim3(2, 64), 256, 0, stream>>>(xar, xar + 524288, wthi, wtlo,
      bigA, nullptr, nullptr, NP, 256, 64, nullptr, nullptr, nullptr, nullptr, nullptr);
  ec_gm_k<128><<<1024, 256, 0, stream>>>(bigA, idx, se2, be2, xar, xar + 1048576);

  // attn 1: qkv (8192x768 fp32 in bigA); x3 split (8192x256) in arena
  gemm_mfma<0><<<dim3(6, 64), 256, 0, stream>>>(xar, xar + 1048576, wthi + 16384, wtlo + 16384,
      bigA, nullptr, nullptr, NP, 768, 128, nullptr, nullptr, nullptr, nullptr, nullptr);
  attn_logits_k<256, 768><<<2048, 256, 0, stream>>>(bigA, idx, attw, 0.0625f);
  attn_apply_k<256, 768><<<2048, 256, 0, stream>>>(bigA, idx, attw, sa1, ba1, xar, xar + 2097152);

  // attn 2: qkv (8192x1536 fp32 in bigA); x4 split (8192x512) in arena
  gemm_mfma<0><<<dim3(12, 64), 256, 0, stream>>>(xar, xar + 2097152, wthi + 114688, wtlo + 114688,
      bigA, nullptr, nullptr, NP, 1536, 256, nullptr, nullptr, nullptr, nullptr, nullptr);
  attn_logits_k<512, 1536><<<2048, 256, 0, stream>>>(bigA, idx, attw, 0.04419417382415922f);
  attn_apply_k<512, 1536><<<4096, 256, 0, stream>>>(bigA, idx, attw, sa2, ba2, xar, xar + 4194304);

  // down: v = x4 @ wtdx + p@Wtd[0:3] (8192x512 fp32 in bigA); xd split
  gemm_mfma<1><<<dim3(4, 64), 256, 0, stream>>>(xar, xar + 4194304, wthi + 507904, wtlo + 507904,
      bigA, nullptr, nullptr, NP, 512, 512, (const float4*)soa, Wtd, nullptr, nullptr, nullptr);
  down_gm_k<<<1024, 256, 0, stream>>>(bigA, (const float4*)soa, Wtd, idx, sd, bd, xdhi, xdlo);

  // global mean term
  colsum_k<<<16, 512, 0, stream>>>(xdhi, xdlo, gpart);
  gterm_k<<<1, 256, 0, stream>>>(gpart, Wu2, su2, bu2, gterm);

  // xu = relu(xd@Wu1*su1 + bu1 + gterm) split (2048x256)
  gemm_mfma<2><<<dim3(2, 16), 256, 0, stream>>>(xdhi, xdlo, wthi + 770048, wtlo + 770048,
      nullptr, xuhi, xulo, NDOWN, 256, 512, nullptr, nullptr, su1, bu1, gterm);
  // h = relu((xu@Wc1 + bc1)*sc + bc) fp32 (2048x128)
  gemm_mfma<3><<<dim3(1, 16), 256, 0, stream>>>(xuhi, xulo, wthi + 901120, wtlo + 901120,
      hbuf, nullptr, nullptr, NDOWN, 128, 256, nullptr, nullptr, sc, bc1, bc);
  // out
  out_k<<<48, 256, 0, stream>>>(hbuf, Wc2, bc2, (float*)d_out);
}

// Round 6
// 327.062 us; speedup vs baseline: 1.8728x; 1.1961x over previous
//
#include <hip/hip_runtime.h>

// DefectNet forward. Round 6:
//  - knn: pass-A (min,idx) tracking + lex bitonic-64 seeds the top-16 list;
//    pass B only fixes lane-collisions (~2 inserts/query); 2 queries/wave
//  - attention K/V stored bf16 (q fp32): halves gather traffic
//  - GEMM MODE 4 epilogue writes q fp32 + k/v bf16 directly

#define NP 8192
#define NDOWN 2048

typedef unsigned long long u64;
typedef __attribute__((ext_vector_type(8))) short short8;
typedef __attribute__((ext_vector_type(8))) unsigned short ushort8;
typedef __attribute__((ext_vector_type(4))) unsigned short us4;
typedef __attribute__((ext_vector_type(4))) float f32x4;

__device__ __forceinline__ bool lexless(float ad, int ai, float bd, int bi) {
  return ad < bd || (ad == bd && ai < bi);
}

__device__ __forceinline__ unsigned short f2bf(float x) {
  unsigned u = __float_as_uint(x);
  unsigned r = (u + 0x7fffu + ((u >> 16) & 1u)) >> 16;
  return (unsigned short)r;
}
__device__ __forceinline__ float bf2f(unsigned short h) {
  return __uint_as_float(((unsigned)h) << 16);
}
__device__ __forceinline__ uint2 pack4h(float a, float b, float c, float d,
                                        unsigned short* l0, unsigned short* l1,
                                        unsigned short* l2, unsigned short* l3) {
  unsigned short h0 = f2bf(a), h1 = f2bf(b), h2 = f2bf(c), h3 = f2bf(d);
  *l0 = f2bf(a - bf2f(h0)); *l1 = f2bf(b - bf2f(h1));
  *l2 = f2bf(c - bf2f(h2)); *l3 = f2bf(d - bf2f(h3));
  return make_uint2((unsigned)h0 | ((unsigned)h1 << 16),
                    (unsigned)h2 | ((unsigned)h3 << 16));
}

// ---------------- prep ----------------
__global__ __launch_bounds__(256) void prep_points_k(const float* __restrict__ pts,
                                                     float4* __restrict__ soa) {
  int i = blockIdx.x * 256 + threadIdx.x;  // 8192
  float x = pts[3 * i], y = pts[3 * i + 1], z = pts[3 * i + 2];
  soa[i] = make_float4(x, y, z, x * x + y * y + z * z);
}

// Transposed weight planes (bf16 hi/lo), t in [0, 933888). Layout as before.
__global__ __launch_bounds__(256) void wsplit_k(
    const float* __restrict__ We2, const float* __restrict__ Wq1,
    const float* __restrict__ Wk1, const float* __restrict__ Wv1,
    const float* __restrict__ Wq2, const float* __restrict__ Wk2,
    const float* __restrict__ Wv2, const float* __restrict__ Wtd,
    const float* __restrict__ Wu1, const float* __restrict__ Wc1,
    unsigned short* __restrict__ whi, unsigned short* __restrict__ wlo) {
  int t = blockIdx.x * 256 + threadIdx.x;
  float v;
  if (t < 16384) {
    int n = t >> 6, k = t & 63;
    if (n < 128) v = We2[k * 128 + n] - We2[(k + 64) * 128 + n];
    else         v = We2[(k + 64) * 128 + (n - 128)];
  } else if (t < 114688) {
    int e = t - 16384;
    int n = e >> 7, k = e & 127;
    if (n < 256)      v = Wq1[k * 256 + n];
    else if (n < 512) v = Wk1[k * 256 + (n - 256)];
    else              v = Wv1[k * 256 + (n - 512)];
  } else if (t < 507904) {
    int e = t - 114688;
    int n = e >> 8, k = e & 255;
    if (n < 512)       v = Wq2[k * 512 + n];
    else if (n < 1024) v = Wk2[k * 512 + (n - 512)];
    else               v = Wv2[k * 512 + (n - 1024)];
  } else if (t < 770048) {
    int e = t - 507904;
    int n = e >> 9, k = e & 511;
    v = Wtd[(3 + k) * 512 + n];
  } else if (t < 901120) {
    int e = t - 770048;
    int n = e >> 9, k = e & 511;
    v = Wu1[k * 256 + n];
  } else {
    int e = t - 901120;
    int n = e >> 8, k = e & 255;
    v = Wc1[k * 128 + n];
  }
  unsigned short hi = f2bf(v);
  unsigned short lo = f2bf(v - bf2f(hi));
  whi[t] = hi;
  wlo[t] = lo;
}

// ---------------- knn ----------------
__device__ __forceinline__ void bitonic_lex64(float& d, int& i, int lane) {
#pragma unroll
  for (int k = 2; k <= 64; k <<= 1) {
#pragma unroll
    for (int j = k >> 1; j >= 1; j >>= 1) {
      float od = __shfl_xor(d, j);
      int oi = __shfl_xor(i, j);
      bool takeMin = (((lane & k) == 0) == ((lane & j) == 0));
      bool less = lexless(od, oi, d, i);
      if (takeMin == less) { d = od; i = oi; }
    }
  }
}

__device__ __forceinline__ void insert16(u64 m, float d, int gidx, int lane,
                                         float& td, int& ti) {
  do {
    int s = (int)__builtin_ctzll(m);
    m &= m - 1;
    float cd = __shfl(d, s);
    int ci = __shfl(gidx, s);
    int p = __popcll(__ballot(lexless(td, ti, cd, ci)));
    if (p < 16) {
      float ud = __shfl_up(td, 1);
      int ui = __shfl_up(ti, 1);
      float ntd = td; int nti = ti;
      if (lane > p && lane < 16) { ntd = ud; nti = ui; }
      if (lane == p) { ntd = cd; nti = ci; }
      td = ntd; ti = nti;
    }
  } while (m);
}

// 512 blocks x 512 thr; each wave handles 2 queries. Pass A: per-lane
// (min,idx); lex bitonic sort seeds the top-16 list + tau. Pass B: dedupe
// (own contributed candidate) + tau filter + exact insert of stragglers.
__global__ __launch_bounds__(512) void knn2_k(const float4* __restrict__ soa,
                                              int* __restrict__ idxout) {
  __shared__ float4 sp[2048];
  const int lane = threadIdx.x & 63;
  const int wid = threadIdx.x >> 6;
  const int q0 = blockIdx.x * 16 + wid * 2;
  const float4 qa = soa[q0];
  const float4 qb = soa[q0 + 1];
  const float INF = __int_as_float(0x7f800000);

  // ---- pass A ----
  float mda = INF, mdb = INF;
  int mia = 0x7fffffff, mib = 0x7fffffff;
  for (int ch = 0; ch < 4; ++ch) {
    __syncthreads();
    for (int j = 0; j < 4; ++j) {
      int e = j * 512 + threadIdx.x;
      sp[e] = soa[ch * 2048 + e];
    }
    __syncthreads();
#pragma unroll 4
    for (int c = 0; c < 32; ++c) {
      const float4 P = sp[c * 64 + lane];
      const int gidx = ch * 2048 + c * 64 + lane;
      const float da = qa.w + P.w - 2.0f * (qa.x * P.x + qa.y * P.y + qa.z * P.z);
      const float db = qb.w + P.w - 2.0f * (qb.x * P.x + qb.y * P.y + qb.z * P.z);
      if (da < mda) { mda = da; mia = gidx; }
      if (db < mdb) { mdb = db; mib = gidx; }
    }
  }
  const int owna = mia;  // own contributed candidate (pre-sort) for dedupe
  const int ownb = mib;
  float sda = mda; int sia = mia;
  float sdb = mdb; int sib = mib;
  bitonic_lex64(sda, sia, lane);
  bitonic_lex64(sdb, sib, lane);

  float tda = (lane < 16) ? sda : INF;
  int tia = (lane < 16) ? sia : 0x7fffffff;
  float tdb = (lane < 16) ? sdb : INF;
  int tib = (lane < 16) ? sib : 0x7fffffff;
  float Tda = __shfl(sda, 15); int Tia = __shfl(sia, 15);
  float Tdb = __shfl(sdb, 15); int Tib = __shfl(sib, 15);
  const float taua = Tda + fabsf(Tda) * 1e-5f + 1e-12f;
  const float taub = Tdb + fabsf(Tdb) * 1e-5f + 1e-12f;

  // ---- pass B ----
  for (int ch = 0; ch < 4; ++ch) {
    __syncthreads();
    for (int j = 0; j < 4; ++j) {
      int e = j * 512 + threadIdx.x;
      sp[e] = soa[ch * 2048 + e];
    }
    __syncthreads();
    for (int c = 0; c < 32; ++c) {
      const float4 P = sp[c * 64 + lane];
      const int gidx = ch * 2048 + c * 64 + lane;
      const float da = qa.w + P.w - 2.0f * (qa.x * P.x + qa.y * P.y + qa.z * P.z);
      const float db = qb.w + P.w - 2.0f * (qb.x * P.x + qb.y * P.y + qb.z * P.z);
      u64 m0 = __ballot((gidx != owna) && (da <= taua) && lexless(da, gidx, Tda, Tia));
      if (m0) {
        insert16(m0, da, gidx, lane, tda, tia);
        Tda = __shfl(tda, 15); Tia = __shfl(tia, 15);
      }
      u64 m1 = __ballot((gidx != ownb) && (db <= taub) && lexless(db, gidx, Tdb, Tib));
      if (m1) {
        insert16(m1, db, gidx, lane, tdb, tib);
        Tdb = __shfl(tdb, 15); Tib = __shfl(tib, 15);
      }
    }
  }
  if (lane < 16) {
    idxout[q0 * 16 + lane] = tia & 8191;
    idxout[(q0 + 1) * 16 + lane] = tib & 8191;
  }
}

// ---------------- edge conv ----------------
__global__ __launch_bounds__(256) void proj1_k(const float4* __restrict__ soa,
                                               const float* __restrict__ We1,
                                               float* __restrict__ bz1) {
  int t = blockIdx.x * 256 + threadIdx.x;  // 8192*128
  int i = t >> 7, c = t & 127;
  float4 P = soa[i];
  float v;
  if (c < 64) {
    v = P.x * (We1[c] - We1[192 + c]) + P.y * (We1[64 + c] - We1[256 + c]) +
        P.z * (We1[128 + c] - We1[320 + c]);
  } else {
    int cc = c & 63;
    v = P.x * We1[192 + cc] + P.y * We1[256 + cc] + P.z * We1[320 + cc];
  }
  bz1[t] = v;
}

template <int C>
__global__ __launch_bounds__(256) void ec_gm_k(const float* __restrict__ bz,
                                               const int* __restrict__ idx,
                                               const float* __restrict__ s,
                                               const float* __restrict__ b,
                                               unsigned short* __restrict__ xhi,
                                               unsigned short* __restrict__ xlo) {
  constexpr int C4 = C / 4;
  int t = blockIdx.x * 256 + threadIdx.x;  // NP*C4
  int i = t / C4, q = t % C4;
  float4 base = *(const float4*)&bz[(size_t)i * (2 * C) + q * 4];
  float4 scl = *(const float4*)&s[q * 4];
  float4 bia = *(const float4*)&b[q * 4];
  float ax = 0.f, ay = 0.f, az = 0.f, aw = 0.f;
  const int* ip = idx + i * 16;
#pragma unroll
  for (int n = 0; n < 16; ++n) {
    int j = ip[n];
    float4 z = *(const float4*)&bz[(size_t)j * (2 * C) + C + q * 4];
    ax = fmaxf(ax, (base.x + z.x) * scl.x + bia.x);
    ay = fmaxf(ay, (base.y + z.y) * scl.y + bia.y);
    az = fmaxf(az, (base.z + z.z) * scl.z + bia.z);
    aw = fmaxf(aw, (base.w + z.w) * scl.w + bia.w);
  }
  unsigned short l0, l1, l2, l3;
  uint2 hp = pack4h(ax, ay, az, aw, &l0, &l1, &l2, &l3);
  uint2 lp = make_uint2((unsigned)l0 | ((unsigned)l1 << 16),
                        (unsigned)l2 | ((unsigned)l3 << 16));
  *(uint2*)&xhi[(size_t)i * C + q * 4] = hp;
  *(uint2*)&xlo[(size_t)i * C + q * 4] = lp;
}

// ---------------- attention ----------------
// q fp32 (NP x C), kv bf16 (NP x 2C): cols [0,C)=k, [C,2C)=v.
template <int C>
__global__ __launch_bounds__(256) void attn_logits_k(const float* __restrict__ qf,
                                                     const unsigned short* __restrict__ kvb,
                                                     const int* __restrict__ idx,
                                                     float* __restrict__ aout,
                                                     float scale) {
  int i = blockIdx.x * 4 + (threadIdx.x >> 6);
  int lane = threadIdx.x & 63;
  constexpr int G = C / 256;
  float4 qv[G];
#pragma unroll
  for (int g = 0; g < G; ++g)
    qv[g] = *(const float4*)&qf[(size_t)i * C + 4 * lane + 256 * g];
  float lg[16];
#pragma unroll
  for (int n = 0; n < 16; ++n) {
    int j = idx[i * 16 + n];
    const unsigned short* kr = kvb + (size_t)j * (2 * C);
    float ssum = 0.f;
#pragma unroll
    for (int g = 0; g < G; ++g) {
      us4 kk = *(const us4*)&kr[4 * lane + 256 * g];
      ssum += qv[g].x * bf2f(kk[0]) + qv[g].y * bf2f(kk[1]) +
              qv[g].z * bf2f(kk[2]) + qv[g].w * bf2f(kk[3]);
    }
    lg[n] = ssum;
  }
#pragma unroll
  for (int n = 0; n < 16; ++n) {
    float vv = lg[n];
    for (int o = 32; o >= 1; o >>= 1) vv += __shfl_xor(vv, o);
    lg[n] = vv * scale;
  }
  float m = lg[0];
#pragma unroll
  for (int n = 1; n < 16; ++n) m = fmaxf(m, lg[n]);
  float ssum = 0.f;
#pragma unroll
  for (int n = 0; n < 16; ++n) { lg[n] = __expf(lg[n] - m); ssum += lg[n]; }
  float inv = 1.f / ssum;
  if (lane == 0) {
#pragma unroll
    for (int n = 0; n < 16; ++n) aout[i * 16 + n] = lg[n] * inv;
  }
}

template <int C>
__global__ __launch_bounds__(256) void attn_apply_k(const unsigned short* __restrict__ kvb,
                                                    const int* __restrict__ idx,
                                                    const float* __restrict__ awp,
                                                    const float* __restrict__ s,
                                                    const float* __restrict__ b,
                                                    unsigned short* __restrict__ xhi,
                                                    unsigned short* __restrict__ xlo) {
  constexpr int C4 = C / 4;
  int t = blockIdx.x * 256 + threadIdx.x;  // NP*C4
  int i = t / C4, q = t % C4;
  float ax = 0.f, ay = 0.f, az = 0.f, aw2 = 0.f;
  const int* ip = idx + i * 16;
  const float* ap = awp + i * 16;
#pragma unroll
  for (int n = 0; n < 16; ++n) {
    int j = ip[n];
    float w = ap[n];
    us4 v4 = *(const us4*)&kvb[(size_t)j * (2 * C) + C + 4 * q];
    ax += w * bf2f(v4[0]); ay += w * bf2f(v4[1]);
    az += w * bf2f(v4[2]); aw2 += w * bf2f(v4[3]);
  }
  float4 scl = *(const float4*)&s[q * 4];
  float4 bia = *(const float4*)&b[q * 4];
  ax = fmaxf(ax * scl.x + bia.x, 0.f);
  ay = fmaxf(ay * scl.y + bia.y, 0.f);
  az = fmaxf(az * scl.z + bia.z, 0.f);
  aw2 = fmaxf(aw2 * scl.w + bia.w, 0.f);
  unsigned short l0, l1, l2, l3;
  uint2 hp = pack4h(ax, ay, az, aw2, &l0, &l1, &l2, &l3);
  uint2 lp = make_uint2((unsigned)l0 | ((unsigned)l1 << 16),
                        (unsigned)l2 | ((unsigned)l3 << 16));
  *(uint2*)&xhi[(size_t)i * C + q * 4] = hp;
  *(uint2*)&xlo[(size_t)i * C + q * 4] = lp;
}

// ---------------- down stage ----------------
__global__ __launch_bounds__(256) void down_gm_k(const float* __restrict__ vbuf,
                                                 const float4* __restrict__ soa,
                                                 const float* __restrict__ Wtd,
                                                 const int* __restrict__ idx,
                                                 const float* __restrict__ sd,
                                                 const float* __restrict__ bd,
                                                 unsigned short* __restrict__ xdhi,
                                                 unsigned short* __restrict__ xdlo) {
  int t = blockIdx.x * 256 + threadIdx.x;  // 2048*128
  int i = t >> 7, q = t & 127;
  int qi = 4 * i;
  float4 qp = soa[qi];
  float4 w0 = *(const float4*)&Wtd[q * 4];
  float4 w1 = *(const float4*)&Wtd[512 + q * 4];
  float4 w2 = *(const float4*)&Wtd[1024 + q * 4];
  float px = qp.x * w0.x + qp.y * w1.x + qp.z * w2.x;
  float py = qp.x * w0.y + qp.y * w1.y + qp.z * w2.y;
  float pz = qp.x * w0.z + qp.y * w1.z + qp.z * w2.z;
  float pw2 = qp.x * w0.w + qp.y * w1.w + qp.z * w2.w;
  float4 scl = *(const float4*)&sd[q * 4];
  float4 bia = *(const float4*)&bd[q * 4];
  float ax = 0.f, ay = 0.f, az = 0.f, aw = 0.f;
  const int* ip = idx + qi * 16;
#pragma unroll
  for (int n = 0; n < 16; ++n) {
    int j = ip[n];
    float4 v = *(const float4*)&vbuf[(size_t)j * 512 + q * 4];
    ax = fmaxf(ax, (v.x - px) * scl.x + bia.x);
    ay = fmaxf(ay, (v.y - py) * scl.y + bia.y);
    az = fmaxf(az, (v.z - pz) * scl.z + bia.z);
    aw = fmaxf(aw, (v.w - pw2) * scl.w + bia.w);
  }
  unsigned short l0, l1, l2, l3;
  uint2 hp = pack4h(ax, ay, az, aw, &l0, &l1, &l2, &l3);
  uint2 lp = make_uint2((unsigned)l0 | ((unsigned)l1 << 16),
                        (unsigned)l2 | ((unsigned)l3 << 16));
  *(uint2*)&xdhi[(size_t)i * 512 + q * 4] = hp;
  *(uint2*)&xdlo[(size_t)i * 512 + q * 4] = lp;
}

__global__ __launch_bounds__(512) void colsum_k(const unsigned short* __restrict__ xdhi,
                                                const unsigned short* __restrict__ xdlo,
                                                float* __restrict__ part) {
  int b = blockIdx.x;           // 16
  int c = threadIdx.x;          // 512
  float s = 0.f;
  for (int r = b * 128; r < (b + 1) * 128; ++r)
    s += bf2f(xdhi[(size_t)r * 512 + c]) + bf2f(xdlo[(size_t)r * 512 + c]);
  part[b * 512 + c] = s;
}

__global__ __launch_bounds__(256) void gterm_k(const float* __restrict__ part,
                                               const float* __restrict__ Wu2,
                                               const float* __restrict__ su2,
                                               const float* __restrict__ bu2,
                                               float* __restrict__ gterm) {
  __shared__ float gm[512];
  int tid = threadIdx.x;
  for (int c = tid; c < 512; c += 256) {
    float s = 0.f;
#pragma unroll
    for (int b = 0; b < 16; ++b) s += part[b * 512 + c];
    gm[c] = s * (1.f / 2048.f);
  }
  __syncthreads();
  float s = 0.f;
  for (int c = 0; c < 512; ++c) s += gm[c] * Wu2[c * 256 + tid];
  gterm[tid] = s * su2[tid] + bu2[tid];
}

// ---------------- MFMA GEMM ----------------
// C = A @ W^T; A hi/lo bf16 planes (M x K), W^T hi/lo (N x K). 3-term split.
// MODE 0: fp32 out. MODE 1: += p@Wtd[0:3], fp32 out. MODE 2: relu(acc*s1+b1+s2)
// split out. MODE 3: relu((acc+b1)*s1+s2) fp32 out. MODE 4: qkv mixed out.
#define LDSROW 80
template <int MODE>
__global__ __launch_bounds__(256) void gemm_mfma(
    const unsigned short* __restrict__ Ahi, const unsigned short* __restrict__ Alo,
    const unsigned short* __restrict__ Bhi, const unsigned short* __restrict__ Blo,
    float* __restrict__ Cf, unsigned short* __restrict__ Chi,
    unsigned short* __restrict__ Clo, int M, int N, int K,
    const float4* __restrict__ soaD, const float* __restrict__ wtd,
    const float* __restrict__ s1, const float* __restrict__ b1,
    const float* __restrict__ s2, int Cq, unsigned short* __restrict__ kvb) {
  __shared__ __align__(16) char smem[4 * 128 * LDSROW];
  char* Ahi_s = smem;
  char* Alo_s = smem + 128 * LDSROW;
  char* Bhi_s = smem + 2 * 128 * LDSROW;
  char* Blo_s = smem + 3 * 128 * LDSROW;

  const int tid = threadIdx.x;
  const int lane = tid & 63;
  const int wid = tid >> 6;
  const int wm = wid >> 1, wn = wid & 1;
  const int bm = blockIdx.y * 128, bn = blockIdx.x * 128;
  const int r16 = lane & 15, kb = lane >> 4;

  f32x4 acc[4][4];
#pragma unroll
  for (int a = 0; a < 4; ++a)
#pragma unroll
    for (int b = 0; b < 4; ++b) acc[a][b] = (f32x4)(0.f);

  for (int k0 = 0; k0 < K; k0 += 32) {
    __syncthreads();
#pragma unroll
    for (int qq = 0; qq < 2; ++qq) {
      int idx8 = qq * 256 + tid;
      int row = idx8 >> 2, sq = idx8 & 3;
      size_t goA = (size_t)(bm + row) * K + k0 + sq * 8;
      size_t goB = (size_t)(bn + row) * K + k0 + sq * 8;
      ushort8 a_h = *(const ushort8*)&Ahi[goA];
      ushort8 a_l = *(const ushort8*)&Alo[goA];
      ushort8 b_h = *(const ushort8*)&Bhi[goB];
      ushort8 b_l = *(const ushort8*)&Blo[goB];
      *(ushort8*)(Ahi_s + row * LDSROW + sq * 16) = a_h;
      *(ushort8*)(Alo_s + row * LDSROW + sq * 16) = a_l;
      *(ushort8*)(Bhi_s + row * LDSROW + sq * 16) = b_h;
      *(ushort8*)(Blo_s + row * LDSROW + sq * 16) = b_l;
    }
    __syncthreads();

    short8 ah[4], al[4];
#pragma unroll
    for (int mi = 0; mi < 4; ++mi) {
      int off = (wm * 64 + mi * 16 + r16) * LDSROW + kb * 16;
      ah[mi] = *(const short8*)(Ahi_s + off);
      al[mi] = *(const short8*)(Alo_s + off);
    }
#pragma unroll
    for (int ni = 0; ni < 4; ++ni) {
      int off = (wn * 64 + ni * 16 + r16) * LDSROW + kb * 16;
      short8 bh = *(const short8*)(Bhi_s + off);
      short8 bl = *(const short8*)(Blo_s + off);
#pragma unroll
      for (int mi = 0; mi < 4; ++mi) {
        acc[mi][ni] = __builtin_amdgcn_mfma_f32_16x16x32_bf16(ah[mi], bh, acc[mi][ni], 0, 0, 0);
        acc[mi][ni] = __builtin_amdgcn_mfma_f32_16x16x32_bf16(ah[mi], bl, acc[mi][ni], 0, 0, 0);
        acc[mi][ni] = __builtin_amdgcn_mfma_f32_16x16x32_bf16(al[mi], bh, acc[mi][ni], 0, 0, 0);
      }
    }
  }

#pragma unroll
  for (int mi = 0; mi < 4; ++mi) {
#pragma unroll
    for (int ni = 0; ni < 4; ++ni) {
      int r0 = bm + wm * 64 + mi * 16 + (lane >> 4) * 4;
      int cc = bn + wn * 64 + ni * 16 + (lane & 15);
      float w0 = 0.f, w1 = 0.f, w2 = 0.f;
      if (MODE == 1) { w0 = wtd[cc]; w1 = wtd[512 + cc]; w2 = wtd[1024 + cc]; }
#pragma unroll
      for (int j = 0; j < 4; ++j) {
        float vv = acc[mi][ni][j];
        int row = r0 + j;
        if (MODE == 1) {
          float4 P = soaD[row];
          vv += P.x * w0 + P.y * w1 + P.z * w2;
        }
        if (MODE == 2) vv = fmaxf(vv * s1[cc] + b1[cc] + s2[cc], 0.f);
        if (MODE == 3) vv = fmaxf((vv + b1[cc]) * s1[cc] + s2[cc], 0.f);
        if (MODE == 2) {
          unsigned short hi = f2bf(vv);
          unsigned short lo = f2bf(vv - bf2f(hi));
          Chi[(size_t)row * N + cc] = hi;
          Clo[(size_t)row * N + cc] = lo;
        } else if (MODE == 4) {
          if (cc < Cq) Cf[(size_t)row * Cq + cc] = vv;
          else kvb[(size_t)row * (2 * Cq) + (cc - Cq)] = f2bf(vv);
        } else {
          Cf[(size_t)row * N + cc] = vv;
        }
      }
    }
  }
}

// ---------------- final ----------------
__global__ __launch_bounds__(256) void out_k(const float* __restrict__ h,
                                             const float* __restrict__ Wc2,
                                             const float* __restrict__ bc2,
                                             float* __restrict__ out) {
  int t = blockIdx.x * 256 + threadIdx.x;  // 2048*6 = 12288
  int i = t / 6, o = t % 6;
  float s = bc2[o];
#pragma unroll 8
  for (int m = 0; m < 128; ++m) s += h[i * 128 + m] * Wc2[m * 6 + o];
  out[t] = s;
}

extern "C" void kernel_launch(void* const* d_in, const int* in_sizes, int n_in,
                              void* d_out, int out_size, void* d_ws, size_t ws_size,
                              hipStream_t stream) {
  const float* pts = (const float*)d_in[0];
  const float* We1 = (const float*)d_in[1];
  const float* se1 = (const float*)d_in[2];
  const float* be1 = (const float*)d_in[3];
  const float* We2 = (const float*)d_in[4];
  const float* se2 = (const float*)d_in[5];
  const float* be2 = (const float*)d_in[6];
  const float* Wq1 = (const float*)d_in[7];
  const float* Wk1 = (const float*)d_in[8];
  const float* Wv1 = (const float*)d_in[9];
  const float* sa1 = (const float*)d_in[10];
  const float* ba1 = (const float*)d_in[11];
  const float* Wq2 = (const float*)d_in[12];
  const float* Wk2 = (const float*)d_in[13];
  const float* Wv2 = (const float*)d_in[14];
  const float* sa2 = (const float*)d_in[15];
  const float* ba2 = (const float*)d_in[16];
  const float* Wtd = (const float*)d_in[17];
  const float* sd  = (const float*)d_in[18];
  const float* bd  = (const float*)d_in[19];
  const float* Wu1 = (const float*)d_in[20];
  const float* su1 = (const float*)d_in[21];
  const float* bu1 = (const float*)d_in[22];
  const float* Wu2 = (const float*)d_in[23];
  const float* su2 = (const float*)d_in[24];
  const float* bu2 = (const float*)d_in[25];
  const float* Wc1 = (const float*)d_in[26];
  const float* bc1 = (const float*)d_in[27];
  const float* sc  = (const float*)d_in[28];
  const float* bc  = (const float*)d_in[29];
  const float* Wc2 = (const float*)d_in[30];
  const float* bc2 = (const float*)d_in[31];

  float* ws = (float*)d_ws;
  if (ws_size < (size_t)19587328 * 4) return;  // ~78.3 MB
  float* soa   = ws;                      // 32768
  int*   idx   = (int*)(ws + 32768);      // 131072 ints
  float* attw  = ws + 163840;             // 131072
  float* gpart = ws + 294912;             // 8192
  float* gterm = ws + 303104;             // 256
  unsigned short* wthi = (unsigned short*)(ws + 303360);   // 933888 ush
  unsigned short* wtlo = (unsigned short*)(ws + 770304);   // 933888 ush
  unsigned short* xar  = (unsigned short*)(ws + 1237248);  // 8388608 ush arena
  unsigned short* xdhi = (unsigned short*)(ws + 5431552);  // 1048576 ush
  unsigned short* xdlo = (unsigned short*)(ws + 5955840);  // 1048576 ush
  unsigned short* xuhi = (unsigned short*)(ws + 6480128);  // 524288 ush
  unsigned short* xulo = (unsigned short*)(ws + 6742272);  // 524288 ush
  float* bufP  = ws + 7004416;            // 4194304 f (bz1/bz2, then h)
  float* qf    = ws + 11198720;           // 4194304 f (q planes, then vbuf)
  unsigned short* kvbf = (unsigned short*)(ws + 15393024); // 8388608 ush

  prep_points_k<<<32, 256, 0, stream>>>(pts, (float4*)soa);
  wsplit_k<<<3648, 256, 0, stream>>>(We2, Wq1, Wk1, Wv1, Wq2, Wk2, Wv2, Wtd, Wu1, Wc1, wthi, wtlo);
  knn2_k<<<512, 512, 0, stream>>>((const float4*)soa, idx);

  // edge conv 1
  proj1_k<<<4096, 256, 0, stream>>>((const float4*)soa, We1, bufP);
  ec_gm_k<64><<<512, 256, 0, stream>>>(bufP, idx, se1, be1, xar, xar + 524288);

  // edge conv 2
  gemm_mfma<0><<<dim3(2, 64), 256, 0, stream>>>(xar, xar + 524288, wthi, wtlo,
      bufP, nullptr, nullptr, NP, 256, 64, nullptr, nullptr, nullptr, nullptr, nullptr, 0, nullptr);
  ec_gm_k<128><<<1024, 256, 0, stream>>>(bufP, idx, se2, be2, xar, xar + 1048576);

  // attn 1
  gemm_mfma<4><<<dim3(6, 64), 256, 0, stream>>>(xar, xar + 1048576, wthi + 16384, wtlo + 16384,
      qf, nullptr, nullptr, NP, 768, 128, nullptr, nullptr, nullptr, nullptr, nullptr, 256, kvbf);
  attn_logits_k<256><<<2048, 256, 0, stream>>>(qf, kvbf, idx, attw, 0.0625f);
  attn_apply_k<256><<<2048, 256, 0, stream>>>(kvbf, idx, attw, sa1, ba1, xar, xar + 2097152);

  // attn 2
  gemm_mfma<4><<<dim3(12, 64), 256, 0, stream>>>(xar, xar + 2097152, wthi + 114688, wtlo + 114688,
      qf, nullptr, nullptr, NP, 1536, 256, nullptr, nullptr, nullptr, nullptr, nullptr, 512, kvbf);
  attn_logits_k<512><<<2048, 256, 0, stream>>>(qf, kvbf, idx, attw, 0.04419417382415922f);
  attn_apply_k<512><<<4096, 256, 0, stream>>>(kvbf, idx, attw, sa2, ba2, xar, xar + 4194304);

  // down
  gemm_mfma<1><<<dim3(4, 64), 256, 0, stream>>>(xar, xar + 4194304, wthi + 507904, wtlo + 507904,
      qf, nullptr, nullptr, NP, 512, 512, (const float4*)soa, Wtd, nullptr, nullptr, nullptr, 0, nullptr);
  down_gm_k<<<1024, 256, 0, stream>>>(qf, (const float4*)soa, Wtd, idx, sd, bd, xdhi, xdlo);

  // global mean term
  colsum_k<<<16, 512, 0, stream>>>(xdhi, xdlo, gpart);
  gterm_k<<<1, 256, 0, stream>>>(gpart, Wu2, su2, bu2, gterm);

  // xu
  gemm_mfma<2><<<dim3(2, 16), 256, 0, stream>>>(xdhi, xdlo, wthi + 770048, wtlo + 770048,
      nullptr, xuhi, xulo, NDOWN, 256, 512, nullptr, nullptr, su1, bu1, gterm, 0, nullptr);
  // h
  gemm_mfma<3><<<dim3(1, 16), 256, 0, stream>>>(xuhi, xulo, wthi + 901120, wtlo + 901120,
      bufP, nullptr, nullptr, NDOWN, 128, 256, nullptr, nullptr, sc, bc1, bc, 0, nullptr);
  // out
  out_k<<<48, 256, 0, stream>>>(bufP, Wc2, bc2, (float*)d_out);
}

// Round 7
// 290.792 us; speedup vs baseline: 2.1064x; 1.1247x over previous
//
#include <hip/hip_runtime.h>

// DefectNet forward. Round 7:
//  - GEMMs: fp16 2-term (A single fp16 plane x W hi/lo fp16), MFMA f16
//  - K/V fp16 (8x better than bf16, same bytes)
//  - knn: 1 query/wave, 1024 blocks (full occupancy)
//  - out_k: 4-way K-split + shfl reduce

#define NP 8192
#define NDOWN 2048

typedef unsigned long long u64;
typedef __attribute__((ext_vector_type(8))) _Float16 half8;
typedef __attribute__((ext_vector_type(4))) unsigned short us4;
typedef __attribute__((ext_vector_type(8))) unsigned short ushort8;
typedef __attribute__((ext_vector_type(4))) float f32x4;

__device__ __forceinline__ bool lexless(float ad, int ai, float bd, int bi) {
  return ad < bd || (ad == bd && ai < bi);
}

__device__ __forceinline__ unsigned short f2h(float x) {
  _Float16 h = (_Float16)x;
  return __builtin_bit_cast(unsigned short, h);
}
__device__ __forceinline__ float h2f(unsigned short u) {
  return (float)__builtin_bit_cast(_Float16, u);
}

// ---------------- prep ----------------
__global__ __launch_bounds__(256) void prep_points_k(const float* __restrict__ pts,
                                                     float4* __restrict__ soa) {
  int i = blockIdx.x * 256 + threadIdx.x;  // 8192
  float x = pts[3 * i], y = pts[3 * i + 1], z = pts[3 * i + 2];
  soa[i] = make_float4(x, y, z, x * x + y * y + z * z);
}

// Transposed weight planes (fp16 hi/lo), t in [0, 933888). Same layout.
__global__ __launch_bounds__(256) void wsplit_k(
    const float* __restrict__ We2, const float* __restrict__ Wq1,
    const float* __restrict__ Wk1, const float* __restrict__ Wv1,
    const float* __restrict__ Wq2, const float* __restrict__ Wk2,
    const float* __restrict__ Wv2, const float* __restrict__ Wtd,
    const float* __restrict__ Wu1, const float* __restrict__ Wc1,
    unsigned short* __restrict__ whi, unsigned short* __restrict__ wlo) {
  int t = blockIdx.x * 256 + threadIdx.x;
  float v;
  if (t < 16384) {
    int n = t >> 6, k = t & 63;
    if (n < 128) v = We2[k * 128 + n] - We2[(k + 64) * 128 + n];
    else         v = We2[(k + 64) * 128 + (n - 128)];
  } else if (t < 114688) {
    int e = t - 16384;
    int n = e >> 7, k = e & 127;
    if (n < 256)      v = Wq1[k * 256 + n];
    else if (n < 512) v = Wk1[k * 256 + (n - 256)];
    else              v = Wv1[k * 256 + (n - 512)];
  } else if (t < 507904) {
    int e = t - 114688;
    int n = e >> 8, k = e & 255;
    if (n < 512)       v = Wq2[k * 512 + n];
    else if (n < 1024) v = Wk2[k * 512 + (n - 512)];
    else               v = Wv2[k * 512 + (n - 1024)];
  } else if (t < 770048) {
    int e = t - 507904;
    int n = e >> 9, k = e & 511;
    v = Wtd[(3 + k) * 512 + n];
  } else if (t < 901120) {
    int e = t - 770048;
    int n = e >> 9, k = e & 511;
    v = Wu1[k * 256 + n];
  } else {
    int e = t - 901120;
    int n = e >> 8, k = e & 255;
    v = Wc1[k * 128 + n];
  }
  unsigned short hi = f2h(v);
  unsigned short lo = f2h(v - h2f(hi));
  whi[t] = hi;
  wlo[t] = lo;
}

// ---------------- knn ----------------
__device__ __forceinline__ void bitonic_lex64(float& d, int& i, int lane) {
#pragma unroll
  for (int k = 2; k <= 64; k <<= 1) {
#pragma unroll
    for (int j = k >> 1; j >= 1; j >>= 1) {
      float od = __shfl_xor(d, j);
      int oi = __shfl_xor(i, j);
      bool takeMin = (((lane & k) == 0) == ((lane & j) == 0));
      bool less = lexless(od, oi, d, i);
      if (takeMin == less) { d = od; i = oi; }
    }
  }
}

__device__ __forceinline__ void insert16(u64 m, float d, int gidx, int lane,
                                         float& td, int& ti) {
  do {
    int s = (int)__builtin_ctzll(m);
    m &= m - 1;
    float cd = __shfl(d, s);
    int ci = __shfl(gidx, s);
    int p = __popcll(__ballot(lexless(td, ti, cd, ci)));
    if (p < 16) {
      float ud = __shfl_up(td, 1);
      int ui = __shfl_up(ti, 1);
      float ntd = td; int nti = ti;
      if (lane > p && lane < 16) { ntd = ud; nti = ui; }
      if (lane == p) { ntd = cd; nti = ci; }
      td = ntd; ti = nti;
    }
  } while (m);
}

// 1024 blocks x 512 thr; each wave handles 1 query (full occupancy).
__global__ __launch_bounds__(512) void knn1_k(const float4* __restrict__ soa,
                                              int* __restrict__ idxout) {
  __shared__ float4 sp[2048];
  const int lane = threadIdx.x & 63;
  const int wid = threadIdx.x >> 6;
  const int q = blockIdx.x * 8 + wid;
  const float4 qp = soa[q];
  const float INF = __int_as_float(0x7f800000);

  // ---- pass A: per-lane (min, idx) over 128 candidates ----
  float md = INF;
  int mi = 0x7fffffff;
  for (int ch = 0; ch < 4; ++ch) {
    __syncthreads();
    for (int j = 0; j < 4; ++j) {
      int e = j * 512 + threadIdx.x;
      sp[e] = soa[ch * 2048 + e];
    }
    __syncthreads();
#pragma unroll 4
    for (int c = 0; c < 32; ++c) {
      const float4 P = sp[c * 64 + lane];
      const int gidx = ch * 2048 + c * 64 + lane;
      const float d = qp.w + P.w - 2.0f * (qp.x * P.x + qp.y * P.y + qp.z * P.z);
      if (d < md) { md = d; mi = gidx; }
    }
  }
  const int own = mi;  // own contributed candidate (pre-sort), for dedupe
  float sd = md; int si = mi;
  bitonic_lex64(sd, si, lane);

  float td = (lane < 16) ? sd : INF;
  int ti = (lane < 16) ? si : 0x7fffffff;
  float Td = __shfl(sd, 15); int Ti = __shfl(si, 15);
  const float tau = Td + fabsf(Td) * 1e-5f + 1e-12f;

  // ---- pass B: straggler inserts ----
  for (int ch = 0; ch < 4; ++ch) {
    __syncthreads();
    for (int j = 0; j < 4; ++j) {
      int e = j * 512 + threadIdx.x;
      sp[e] = soa[ch * 2048 + e];
    }
    __syncthreads();
    for (int c = 0; c < 32; ++c) {
      const float4 P = sp[c * 64 + lane];
      const int gidx = ch * 2048 + c * 64 + lane;
      const float d = qp.w + P.w - 2.0f * (qp.x * P.x + qp.y * P.y + qp.z * P.z);
      u64 m = __ballot((gidx != own) && (d <= tau) && lexless(d, gidx, Td, Ti));
      if (m) {
        insert16(m, d, gidx, lane, td, ti);
        Td = __shfl(td, 15); Ti = __shfl(ti, 15);
      }
    }
  }
  if (lane < 16) idxout[q * 16 + lane] = ti & 8191;
}

// ---------------- edge conv ----------------
__global__ __launch_bounds__(256) void proj1_k(const float4* __restrict__ soa,
                                               const float* __restrict__ We1,
                                               float* __restrict__ bz1) {
  int t = blockIdx.x * 256 + threadIdx.x;  // 8192*128
  int i = t >> 7, c = t & 127;
  float4 P = soa[i];
  float v;
  if (c < 64) {
    v = P.x * (We1[c] - We1[192 + c]) + P.y * (We1[64 + c] - We1[256 + c]) +
        P.z * (We1[128 + c] - We1[320 + c]);
  } else {
    int cc = c & 63;
    v = P.x * We1[192 + cc] + P.y * We1[256 + cc] + P.z * We1[320 + cc];
  }
  bz1[t] = v;
}

// x[i][c] = max_n relu((base[i][c] + z[j][c]) * s + b); fp16 single output.
template <int C>
__global__ __launch_bounds__(256) void ec_gm_k(const float* __restrict__ bz,
                                               const int* __restrict__ idx,
                                               const float* __restrict__ s,
                                               const float* __restrict__ b,
                                               unsigned short* __restrict__ xo) {
  constexpr int C4 = C / 4;
  int t = blockIdx.x * 256 + threadIdx.x;  // NP*C4
  int i = t / C4, q = t % C4;
  float4 base = *(const float4*)&bz[(size_t)i * (2 * C) + q * 4];
  float4 scl = *(const float4*)&s[q * 4];
  float4 bia = *(const float4*)&b[q * 4];
  float ax = 0.f, ay = 0.f, az = 0.f, aw = 0.f;
  const int* ip = idx + i * 16;
#pragma unroll
  for (int n = 0; n < 16; ++n) {
    int j = ip[n];
    float4 z = *(const float4*)&bz[(size_t)j * (2 * C) + C + q * 4];
    ax = fmaxf(ax, (base.x + z.x) * scl.x + bia.x);
    ay = fmaxf(ay, (base.y + z.y) * scl.y + bia.y);
    az = fmaxf(az, (base.z + z.z) * scl.z + bia.z);
    aw = fmaxf(aw, (base.w + z.w) * scl.w + bia.w);
  }
  us4 o;
  o[0] = f2h(ax); o[1] = f2h(ay); o[2] = f2h(az); o[3] = f2h(aw);
  *(us4*)&xo[(size_t)i * C + q * 4] = o;
}

// ---------------- attention ----------------
// q fp32 (NP x C), kv fp16 (NP x 2C): cols [0,C)=k, [C,2C)=v.
template <int C>
__global__ __launch_bounds__(256) void attn_logits_k(const float* __restrict__ qf,
                                                     const unsigned short* __restrict__ kvb,
                                                     const int* __restrict__ idx,
                                                     float* __restrict__ aout,
                                                     float scale) {
  int i = blockIdx.x * 4 + (threadIdx.x >> 6);
  int lane = threadIdx.x & 63;
  constexpr int G = C / 256;
  float4 qv[G];
#pragma unroll
  for (int g = 0; g < G; ++g)
    qv[g] = *(const float4*)&qf[(size_t)i * C + 4 * lane + 256 * g];
  float lg[16];
#pragma unroll
  for (int n = 0; n < 16; ++n) {
    int j = idx[i * 16 + n];
    const unsigned short* kr = kvb + (size_t)j * (2 * C);
    float ssum = 0.f;
#pragma unroll
    for (int g = 0; g < G; ++g) {
      us4 kk = *(const us4*)&kr[4 * lane + 256 * g];
      ssum += qv[g].x * h2f(kk[0]) + qv[g].y * h2f(kk[1]) +
              qv[g].z * h2f(kk[2]) + qv[g].w * h2f(kk[3]);
    }
    lg[n] = ssum;
  }
#pragma unroll
  for (int n = 0; n < 16; ++n) {
    float vv = lg[n];
    for (int o = 32; o >= 1; o >>= 1) vv += __shfl_xor(vv, o);
    lg[n] = vv * scale;
  }
  float m = lg[0];
#pragma unroll
  for (int n = 1; n < 16; ++n) m = fmaxf(m, lg[n]);
  float ssum = 0.f;
#pragma unroll
  for (int n = 0; n < 16; ++n) { lg[n] = __expf(lg[n] - m); ssum += lg[n]; }
  float inv = 1.f / ssum;
  if (lane == 0) {
#pragma unroll
    for (int n = 0; n < 16; ++n) aout[i * 16 + n] = lg[n] * inv;
  }
}

template <int C>
__global__ __launch_bounds__(256) void attn_apply_k(const unsigned short* __restrict__ kvb,
                                                    const int* __restrict__ idx,
                                                    const float* __restrict__ awp,
                                                    const float* __restrict__ s,
                                                    const float* __restrict__ b,
                                                    unsigned short* __restrict__ xo) {
  constexpr int C4 = C / 4;
  int t = blockIdx.x * 256 + threadIdx.x;  // NP*C4
  int i = t / C4, q = t % C4;
  float ax = 0.f, ay = 0.f, az = 0.f, aw2 = 0.f;
  const int* ip = idx + i * 16;
  const float* ap = awp + i * 16;
#pragma unroll
  for (int n = 0; n < 16; ++n) {
    int j = ip[n];
    float w = ap[n];
    us4 v4 = *(const us4*)&kvb[(size_t)j * (2 * C) + C + 4 * q];
    ax += w * h2f(v4[0]); ay += w * h2f(v4[1]);
    az += w * h2f(v4[2]); aw2 += w * h2f(v4[3]);
  }
  float4 scl = *(const float4*)&s[q * 4];
  float4 bia = *(const float4*)&b[q * 4];
  ax = fmaxf(ax * scl.x + bia.x, 0.f);
  ay = fmaxf(ay * scl.y + bia.y, 0.f);
  az = fmaxf(az * scl.z + bia.z, 0.f);
  aw2 = fmaxf(aw2 * scl.w + bia.w, 0.f);
  us4 o;
  o[0] = f2h(ax); o[1] = f2h(ay); o[2] = f2h(az); o[3] = f2h(aw2);
  *(us4*)&xo[(size_t)i * C + q * 4] = o;
}

// ---------------- down stage ----------------
__global__ __launch_bounds__(256) void down_gm_k(const float* __restrict__ vbuf,
                                                 const float4* __restrict__ soa,
                                                 const float* __restrict__ Wtd,
                                                 const int* __restrict__ idx,
                                                 const float* __restrict__ sd,
                                                 const float* __restrict__ bd,
                                                 unsigned short* __restrict__ xd) {
  int t = blockIdx.x * 256 + threadIdx.x;  // 2048*128
  int i = t >> 7, q = t & 127;
  int qi = 4 * i;
  float4 qp = soa[qi];
  float4 w0 = *(const float4*)&Wtd[q * 4];
  float4 w1 = *(const float4*)&Wtd[512 + q * 4];
  float4 w2 = *(const float4*)&Wtd[1024 + q * 4];
  float px = qp.x * w0.x + qp.y * w1.x + qp.z * w2.x;
  float py = qp.x * w0.y + qp.y * w1.y + qp.z * w2.y;
  float pz = qp.x * w0.z + qp.y * w1.z + qp.z * w2.z;
  float pw2 = qp.x * w0.w + qp.y * w1.w + qp.z * w2.w;
  float4 scl = *(const float4*)&sd[q * 4];
  float4 bia = *(const float4*)&bd[q * 4];
  float ax = 0.f, ay = 0.f, az = 0.f, aw = 0.f;
  const int* ip = idx + qi * 16;
#pragma unroll
  for (int n = 0; n < 16; ++n) {
    int j = ip[n];
    float4 v = *(const float4*)&vbuf[(size_t)j * 512 + q * 4];
    ax = fmaxf(ax, (v.x - px) * scl.x + bia.x);
    ay = fmaxf(ay, (v.y - py) * scl.y + bia.y);
    az = fmaxf(az, (v.z - pz) * scl.z + bia.z);
    aw = fmaxf(aw, (v.w - pw2) * scl.w + bia.w);
  }
  us4 o;
  o[0] = f2h(ax); o[1] = f2h(ay); o[2] = f2h(az); o[3] = f2h(aw);
  *(us4*)&xd[(size_t)i * 512 + q * 4] = o;
}

__global__ __launch_bounds__(512) void colsum_k(const unsigned short* __restrict__ xd,
                                                float* __restrict__ part) {
  int b = blockIdx.x;           // 16
  int c = threadIdx.x;          // 512
  float s = 0.f;
  for (int r = b * 128; r < (b + 1) * 128; ++r) s += h2f(xd[(size_t)r * 512 + c]);
  part[b * 512 + c] = s;
}

__global__ __launch_bounds__(256) void gterm_k(const float* __restrict__ part,
                                               const float* __restrict__ Wu2,
                                               const float* __restrict__ su2,
                                               const float* __restrict__ bu2,
                                               float* __restrict__ gterm) {
  __shared__ float gm[512];
  int tid = threadIdx.x;
  for (int c = tid; c < 512; c += 256) {
    float s = 0.f;
#pragma unroll
    for (int b = 0; b < 16; ++b) s += part[b * 512 + c];
    gm[c] = s * (1.f / 2048.f);
  }
  __syncthreads();
  float s = 0.f;
  for (int c = 0; c < 512; ++c) s += gm[c] * Wu2[c * 256 + tid];
  gterm[tid] = s * su2[tid] + bu2[tid];
}

// ---------------- MFMA GEMM (fp16 2-term) ----------------
// C = A @ W^T; A fp16 plane (M x K), W^T fp16 hi/lo (N x K).
// 128x128 tile, BK=32, 4 waves. acc = A*Whi + A*Wlo.
// MODE 0: fp32 out. MODE 1: += p@Wtd[0:3], fp32 out. MODE 2: relu(acc*s1+b1+s2)
// fp16 out. MODE 3: relu((acc+b1)*s1+s2) fp32 out. MODE 4: q fp32 + kv fp16.
#define LDSROW 80
template <int MODE>
__global__ __launch_bounds__(256) void gemm_mfma(
    const unsigned short* __restrict__ A,
    const unsigned short* __restrict__ Bhi, const unsigned short* __restrict__ Blo,
    float* __restrict__ Cf, unsigned short* __restrict__ Ch,
    int M, int N, int K,
    const float4* __restrict__ soaD, const float* __restrict__ wtd,
    const float* __restrict__ s1, const float* __restrict__ b1,
    const float* __restrict__ s2, int Cq, unsigned short* __restrict__ kvb) {
  __shared__ __align__(16) char smem[3 * 128 * LDSROW];
  char* A_s = smem;
  char* Bh_s = smem + 128 * LDSROW;
  char* Bl_s = smem + 2 * 128 * LDSROW;

  const int tid = threadIdx.x;
  const int lane = tid & 63;
  const int wid = tid >> 6;
  const int wm = wid >> 1, wn = wid & 1;
  const int bm = blockIdx.y * 128, bn = blockIdx.x * 128;
  const int r16 = lane & 15, kb = lane >> 4;

  f32x4 acc[4][4];
#pragma unroll
  for (int a = 0; a < 4; ++a)
#pragma unroll
    for (int b = 0; b < 4; ++b) acc[a][b] = (f32x4)(0.f);

  for (int k0 = 0; k0 < K; k0 += 32) {
    __syncthreads();
#pragma unroll
    for (int qq = 0; qq < 2; ++qq) {
      int idx8 = qq * 256 + tid;
      int row = idx8 >> 2, sq = idx8 & 3;
      size_t goA = (size_t)(bm + row) * K + k0 + sq * 8;
      size_t goB = (size_t)(bn + row) * K + k0 + sq * 8;
      ushort8 a_v = *(const ushort8*)&A[goA];
      ushort8 b_h = *(const ushort8*)&Bhi[goB];
      ushort8 b_l = *(const ushort8*)&Blo[goB];
      *(ushort8*)(A_s + row * LDSROW + sq * 16) = a_v;
      *(ushort8*)(Bh_s + row * LDSROW + sq * 16) = b_h;
      *(ushort8*)(Bl_s + row * LDSROW + sq * 16) = b_l;
    }
    __syncthreads();

    half8 ah[4];
#pragma unroll
    for (int mi = 0; mi < 4; ++mi) {
      int off = (wm * 64 + mi * 16 + r16) * LDSROW + kb * 16;
      ah[mi] = *(const half8*)(A_s + off);
    }
#pragma unroll
    for (int ni = 0; ni < 4; ++ni) {
      int off = (wn * 64 + ni * 16 + r16) * LDSROW + kb * 16;
      half8 bh = *(const half8*)(Bh_s + off);
      half8 bl = *(const half8*)(Bl_s + off);
#pragma unroll
      for (int mi = 0; mi < 4; ++mi) {
        acc[mi][ni] = __builtin_amdgcn_mfma_f32_16x16x32_f16(ah[mi], bh, acc[mi][ni], 0, 0, 0);
        acc[mi][ni] = __builtin_amdgcn_mfma_f32_16x16x32_f16(ah[mi], bl, acc[mi][ni], 0, 0, 0);
      }
    }
  }

#pragma unroll
  for (int mi = 0; mi < 4; ++mi) {
#pragma unroll
    for (int ni = 0; ni < 4; ++ni) {
      int r0 = bm + wm * 64 + mi * 16 + (lane >> 4) * 4;
      int cc = bn + wn * 64 + ni * 16 + (lane & 15);
      float w0 = 0.f, w1 = 0.f, w2 = 0.f;
      if (MODE == 1) { w0 = wtd[cc]; w1 = wtd[512 + cc]; w2 = wtd[1024 + cc]; }
#pragma unroll
      for (int j = 0; j < 4; ++j) {
        float vv = acc[mi][ni][j];
        int row = r0 + j;
        if (MODE == 1) {
          float4 P = soaD[row];
          vv += P.x * w0 + P.y * w1 + P.z * w2;
        }
        if (MODE == 2) vv = fmaxf(vv * s1[cc] + b1[cc] + s2[cc], 0.f);
        if (MODE == 3) vv = fmaxf((vv + b1[cc]) * s1[cc] + s2[cc], 0.f);
        if (MODE == 2) {
          Ch[(size_t)row * N + cc] = f2h(vv);
        } else if (MODE == 4) {
          if (cc < Cq) Cf[(size_t)row * Cq + cc] = vv;
          else kvb[(size_t)row * (2 * Cq) + (cc - Cq)] = f2h(vv);
        } else {
          Cf[(size_t)row * N + cc] = vv;
        }
      }
    }
  }
}

// ---------------- final ----------------
// 4-way K-split; lanes 4t..4t+3 share an (i,o) pair; shfl_xor reduce.
__global__ __launch_bounds__(256) void out_k(const float* __restrict__ h,
                                             const float* __restrict__ Wc2,
                                             const float* __restrict__ bc2,
                                             float* __restrict__ out) {
  int t = blockIdx.x * 256 + threadIdx.x;  // 49152
  int pair = t >> 2, kq = t & 3;           // pair < 12288
  int i = pair / 6, o = pair % 6;
  float s = 0.f;
#pragma unroll 8
  for (int m = kq * 32; m < kq * 32 + 32; ++m) s += h[i * 128 + m] * Wc2[m * 6 + o];
  s += __shfl_xor(s, 1);
  s += __shfl_xor(s, 2);
  if (kq == 0) out[pair] = s + bc2[o];
}

extern "C" void kernel_launch(void* const* d_in, const int* in_sizes, int n_in,
                              void* d_out, int out_size, void* d_ws, size_t ws_size,
                              hipStream_t stream) {
  const float* pts = (const float*)d_in[0];
  const float* We1 = (const float*)d_in[1];
  const float* se1 = (const float*)d_in[2];
  const float* be1 = (const float*)d_in[3];
  const float* We2 = (const float*)d_in[4];
  const float* se2 = (const float*)d_in[5];
  const float* be2 = (const float*)d_in[6];
  const float* Wq1 = (const float*)d_in[7];
  const float* Wk1 = (const float*)d_in[8];
  const float* Wv1 = (const float*)d_in[9];
  const float* sa1 = (const float*)d_in[10];
  const float* ba1 = (const float*)d_in[11];
  const float* Wq2 = (const float*)d_in[12];
  const float* Wk2 = (const float*)d_in[13];
  const float* Wv2 = (const float*)d_in[14];
  const float* sa2 = (const float*)d_in[15];
  const float* ba2 = (const float*)d_in[16];
  const float* Wtd = (const float*)d_in[17];
  const float* sd  = (const float*)d_in[18];
  const float* bd  = (const float*)d_in[19];
  const float* Wu1 = (const float*)d_in[20];
  const float* su1 = (const float*)d_in[21];
  const float* bu1 = (const float*)d_in[22];
  const float* Wu2 = (const float*)d_in[23];
  const float* su2 = (const float*)d_in[24];
  const float* bu2 = (const float*)d_in[25];
  const float* Wc1 = (const float*)d_in[26];
  const float* bc1 = (const float*)d_in[27];
  const float* sc  = (const float*)d_in[28];
  const float* bc  = (const float*)d_in[29];
  const float* Wc2 = (const float*)d_in[30];
  const float* bc2 = (const float*)d_in[31];

  float* ws = (float*)d_ws;
  if (ws_size < (size_t)16703744 * 4) return;  // ~66.8 MB
  float* soa   = ws;                      // 32768
  int*   idx   = (int*)(ws + 32768);      // 131072 ints
  float* attw  = ws + 163840;             // 131072
  float* gpart = ws + 294912;             // 8192
  float* gterm = ws + 303104;             // 256
  unsigned short* wthi = (unsigned short*)(ws + 303360);   // 933888 ush
  unsigned short* wtlo = (unsigned short*)(ws + 770304);   // 933888 ush
  unsigned short* x1   = (unsigned short*)(ws + 1237248);  // 524288 ush
  unsigned short* x2   = (unsigned short*)(ws + 1499392);  // 1048576 ush
  unsigned short* x3   = (unsigned short*)(ws + 2023680);  // 2097152 ush
  unsigned short* x4   = (unsigned short*)(ws + 3072256);  // 4194304 ush
  unsigned short* xd   = (unsigned short*)(ws + 5169408);  // 1048576 ush
  unsigned short* xu   = (unsigned short*)(ws + 5693696);  // 524288 ush
  float* bufP  = ws + 5955840;            // 2097152 f (bz1/bz2)
  float* qf    = ws + 8052992;            // 4194304 f (q planes / vbuf)
  unsigned short* kvb = (unsigned short*)(ws + 12247296);  // 8388608 ush
  float* hbuf  = ws + 16441600;           // 262144 f

  prep_points_k<<<32, 256, 0, stream>>>(pts, (float4*)soa);
  wsplit_k<<<3648, 256, 0, stream>>>(We2, Wq1, Wk1, Wv1, Wq2, Wk2, Wv2, Wtd, Wu1, Wc1, wthi, wtlo);
  knn1_k<<<1024, 512, 0, stream>>>((const float4*)soa, idx);

  // edge conv 1
  proj1_k<<<4096, 256, 0, stream>>>((const float4*)soa, We1, bufP);
  ec_gm_k<64><<<512, 256, 0, stream>>>(bufP, idx, se1, be1, x1);

  // edge conv 2
  gemm_mfma<0><<<dim3(2, 64), 256, 0, stream>>>(x1, wthi, wtlo,
      bufP, nullptr, NP, 256, 64, nullptr, nullptr, nullptr, nullptr, nullptr, 0, nullptr);
  ec_gm_k<128><<<1024, 256, 0, stream>>>(bufP, idx, se2, be2, x2);

  // attn 1
  gemm_mfma<4><<<dim3(6, 64), 256, 0, stream>>>(x2, wthi + 16384, wtlo + 16384,
      qf, nullptr, NP, 768, 128, nullptr, nullptr, nullptr, nullptr, nullptr, 256, kvb);
  attn_logits_k<256><<<2048, 256, 0, stream>>>(qf, kvb, idx, attw, 0.0625f);
  attn_apply_k<256><<<2048, 256, 0, stream>>>(kvb, idx, attw, sa1, ba1, x3);

  // attn 2
  gemm_mfma<4><<<dim3(12, 64), 256, 0, stream>>>(x3, wthi + 114688, wtlo + 114688,
      qf, nullptr, NP, 1536, 256, nullptr, nullptr, nullptr, nullptr, nullptr, 512, kvb);
  attn_logits_k<512><<<2048, 256, 0, stream>>>(qf, kvb, idx, attw, 0.04419417382415922f);
  attn_apply_k<512><<<4096, 256, 0, stream>>>(kvb, idx, attw, sa2, ba2, x4);

  // down
  gemm_mfma<1><<<dim3(4, 64), 256, 0, stream>>>(x4, wthi + 507904, wtlo + 507904,
      qf, nullptr, NP, 512, 512, (const float4*)soa, Wtd, nullptr, nullptr, nullptr, 0, nullptr);
  down_gm_k<<<1024, 256, 0, stream>>>(qf, (const float4*)soa, Wtd, idx, sd, bd, xd);

  // global mean term
  colsum_k<<<16, 512, 0, stream>>>(xd, gpart);
  gterm_k<<<1, 256, 0, stream>>>(gpart, Wu2, su2, bu2, gterm);

  // xu
  gemm_mfma<2><<<dim3(2, 16), 256, 0, stream>>>(xd, wthi + 770048, wtlo + 770048,
      nullptr, xu, NDOWN, 256, 512, nullptr, nullptr, su1, bu1, gterm, 0, nullptr);
  // h
  gemm_mfma<3><<<dim3(1, 16), 256, 0, stream>>>(xu, wthi + 901120, wtlo + 901120,
      hbuf, nullptr, NDOWN, 128, 256, nullptr, nullptr, sc, bc1, bc, 0, nullptr);
  // out
  out_k<<<192, 256, 0, stream>>>(hbuf, Wc2, bc2, (float*)d_out);
}

// Round 8
// 264.812 us; speedup vs baseline: 2.3130x; 1.0981x over previous
//
#include <hip/hip_runtime.h>

// DefectNet forward. Round 8:
//  - GEMMs: 1-term fp16 (A fp16 x Whi fp16) - knn-reorder noise floor makes
//    the 2nd weight term unmeasurable; halves MFMA + staging
//  - knn pass B: branch-free stream + LDS candidate collection + uniform
//    drain inserts (removes 128 serialized ballots/query); global-scan
//    fallback on buffer overflow (exactness unconditional)

#define NP 8192
#define NDOWN 2048
#define KCAP 48

typedef unsigned long long u64;
typedef __attribute__((ext_vector_type(8))) _Float16 half8;
typedef __attribute__((ext_vector_type(4))) unsigned short us4;
typedef __attribute__((ext_vector_type(8))) unsigned short ushort8;
typedef __attribute__((ext_vector_type(4))) float f32x4;

__device__ __forceinline__ bool lexless(float ad, int ai, float bd, int bi) {
  return ad < bd || (ad == bd && ai < bi);
}

__device__ __forceinline__ unsigned short f2h(float x) {
  _Float16 h = (_Float16)x;
  return __builtin_bit_cast(unsigned short, h);
}
__device__ __forceinline__ float h2f(unsigned short u) {
  return (float)__builtin_bit_cast(_Float16, u);
}

// ---------------- prep ----------------
__global__ __launch_bounds__(256) void prep_points_k(const float* __restrict__ pts,
                                                     float4* __restrict__ soa) {
  int i = blockIdx.x * 256 + threadIdx.x;  // 8192
  float x = pts[3 * i], y = pts[3 * i + 1], z = pts[3 * i + 2];
  soa[i] = make_float4(x, y, z, x * x + y * y + z * z);
}

// Transposed weight planes (fp16), t in [0, 933888). Same layout as before.
__global__ __launch_bounds__(256) void wsplit_k(
    const float* __restrict__ We2, const float* __restrict__ Wq1,
    const float* __restrict__ Wk1, const float* __restrict__ Wv1,
    const float* __restrict__ Wq2, const float* __restrict__ Wk2,
    const float* __restrict__ Wv2, const float* __restrict__ Wtd,
    const float* __restrict__ Wu1, const float* __restrict__ Wc1,
    unsigned short* __restrict__ whi) {
  int t = blockIdx.x * 256 + threadIdx.x;
  float v;
  if (t < 16384) {
    int n = t >> 6, k = t & 63;
    if (n < 128) v = We2[k * 128 + n] - We2[(k + 64) * 128 + n];
    else         v = We2[(k + 64) * 128 + (n - 128)];
  } else if (t < 114688) {
    int e = t - 16384;
    int n = e >> 7, k = e & 127;
    if (n < 256)      v = Wq1[k * 256 + n];
    else if (n < 512) v = Wk1[k * 256 + (n - 256)];
    else              v = Wv1[k * 256 + (n - 512)];
  } else if (t < 507904) {
    int e = t - 114688;
    int n = e >> 8, k = e & 255;
    if (n < 512)       v = Wq2[k * 512 + n];
    else if (n < 1024) v = Wk2[k * 512 + (n - 512)];
    else               v = Wv2[k * 512 + (n - 1024)];
  } else if (t < 770048) {
    int e = t - 507904;
    int n = e >> 9, k = e & 511;
    v = Wtd[(3 + k) * 512 + n];
  } else if (t < 901120) {
    int e = t - 770048;
    int n = e >> 9, k = e & 511;
    v = Wu1[k * 256 + n];
  } else {
    int e = t - 901120;
    int n = e >> 8, k = e & 255;
    v = Wc1[k * 128 + n];
  }
  whi[t] = f2h(v);
}

// ---------------- knn ----------------
__device__ __forceinline__ void bitonic_lex64(float& d, int& i, int lane) {
#pragma unroll
  for (int k = 2; k <= 64; k <<= 1) {
#pragma unroll
    for (int j = k >> 1; j >= 1; j >>= 1) {
      float od = __shfl_xor(d, j);
      int oi = __shfl_xor(i, j);
      bool takeMin = (((lane & k) == 0) == ((lane & j) == 0));
      bool less = lexless(od, oi, d, i);
      if (takeMin == less) { d = od; i = oi; }
    }
  }
}

__device__ __forceinline__ void insert1(float cd, int ci, int lane,
                                        float& td, int& ti) {
  int p = __popcll(__ballot(lexless(td, ti, cd, ci)));
  if (p < 16) {
    float ud = __shfl_up(td, 1);
    int ui = __shfl_up(ti, 1);
    float ntd = td; int nti = ti;
    if (lane > p && lane < 16) { ntd = ud; nti = ui; }
    if (lane == p) { ntd = cd; nti = ci; }
    td = ntd; ti = nti;
  }
}

// 1024 blocks x 512 thr; wave handles 1 query.
// Pass A: per-lane (min,idx) -> bitonic lex sort seeds list + tau.
// Pass B: branch-free stream; hits (d<=tau, not own) -> LDS buffer (atomic);
// drain with uniform exact inserts. Overflow -> global-scan fallback.
__global__ __launch_bounds__(512) void knn_k(const float4* __restrict__ soa,
                                             int* __restrict__ idxout) {
  __shared__ float4 sp[2048];
  __shared__ float cb_d[8][KCAP];
  __shared__ int cb_i[8][KCAP];
  __shared__ int ccnt[8];
  const int lane = threadIdx.x & 63;
  const int wid = threadIdx.x >> 6;
  const int q = blockIdx.x * 8 + wid;
  const float4 qp = soa[q];
  const float qx2 = -2.f * qp.x, qy2 = -2.f * qp.y, qz2 = -2.f * qp.z;
  const float INF = __int_as_float(0x7f800000);
  if (lane == 0) ccnt[wid] = 0;

  // ---- pass A ----
  float md = INF;
  int mi = 0x7fffffff;
  for (int ch = 0; ch < 4; ++ch) {
    __syncthreads();
    for (int j = 0; j < 4; ++j) {
      int e = j * 512 + threadIdx.x;
      sp[e] = soa[ch * 2048 + e];
    }
    __syncthreads();
#pragma unroll 4
    for (int c = 0; c < 32; ++c) {
      const float4 P = sp[c * 64 + lane];
      float m = fmaf(qx2, P.x, qp.w);
      m = fmaf(qy2, P.y, m);
      m = fmaf(qz2, P.z, m);
      const float d = m + P.w;
      const int gidx = ch * 2048 + c * 64 + lane;
      if (d < md) { md = d; mi = gidx; }
    }
  }
  const int own = mi;  // candidate this lane contributed (for dedupe)
  float sd = md; int si = mi;
  bitonic_lex64(sd, si, lane);

  float td = (lane < 16) ? sd : INF;
  int ti = (lane < 16) ? si : 0x7fffffff;
  float Td = __shfl(sd, 15); int Ti = __shfl(si, 15);
  const float tau = Td + fabsf(Td) * 1e-5f + 1e-12f;

  // ---- pass B: stream & collect ----
  for (int ch = 0; ch < 4; ++ch) {
    __syncthreads();
    for (int j = 0; j < 4; ++j) {
      int e = j * 512 + threadIdx.x;
      sp[e] = soa[ch * 2048 + e];
    }
    __syncthreads();
#pragma unroll 4
    for (int c = 0; c < 32; ++c) {
      const float4 P = sp[c * 64 + lane];
      float m = fmaf(qx2, P.x, qp.w);
      m = fmaf(qy2, P.y, m);
      m = fmaf(qz2, P.z, m);
      const float d = m + P.w;
      const int gidx = ch * 2048 + c * 64 + lane;
      if (d <= tau && gidx != own) {
        int slot = atomicAdd(&ccnt[wid], 1);
        if (slot < KCAP) { cb_d[wid][slot] = d; cb_i[wid][slot] = gidx; }
      }
    }
  }
  int n = ccnt[wid];
  if (n > KCAP) {
    // degenerate (many ties): exact wave-local global rescan
    for (int base = 0; base < 8192; base += 64) {
      const float4 P = soa[base + lane];
      float m = fmaf(qx2, P.x, qp.w);
      m = fmaf(qy2, P.y, m);
      m = fmaf(qz2, P.z, m);
      const float d = m + P.w;
      const int gidx = base + lane;
      u64 mk = __ballot(d <= tau && gidx != own && lexless(d, gidx, Td, Ti));
      while (mk) {
        int s = (int)__builtin_ctzll(mk);
        mk &= mk - 1;
        float cd = __shfl(d, s);
        int ci = __shfl(gidx, s);
        insert1(cd, ci, lane, td, ti);
      }
      Td = __shfl(td, 15); Ti = __shfl(ti, 15);
    }
  } else {
    for (int k2 = 0; k2 < n; ++k2) {
      float cd = cb_d[wid][k2];
      int ci = cb_i[wid][k2];
      if (lexless(cd, ci, Td, Ti)) {
        insert1(cd, ci, lane, td, ti);
        Td = __shfl(td, 15); Ti = __shfl(ti, 15);
      }
    }
  }
  if (lane < 16) idxout[q * 16 + lane] = ti & 8191;
}

// ---------------- edge conv ----------------
__global__ __launch_bounds__(256) void proj1_k(const float4* __restrict__ soa,
                                               const float* __restrict__ We1,
                                               float* __restrict__ bz1) {
  int t = blockIdx.x * 256 + threadIdx.x;  // 8192*128
  int i = t >> 7, c = t & 127;
  float4 P = soa[i];
  float v;
  if (c < 64) {
    v = P.x * (We1[c] - We1[192 + c]) + P.y * (We1[64 + c] - We1[256 + c]) +
        P.z * (We1[128 + c] - We1[320 + c]);
  } else {
    int cc = c & 63;
    v = P.x * We1[192 + cc] + P.y * We1[256 + cc] + P.z * We1[320 + cc];
  }
  bz1[t] = v;
}

// x[i][c] = max_n relu((base[i][c] + z[j][c]) * s + b); fp16 output.
template <int C>
__global__ __launch_bounds__(256) void ec_gm_k(const float* __restrict__ bz,
                                               const int* __restrict__ idx,
                                               const float* __restrict__ s,
                                               const float* __restrict__ b,
                                               unsigned short* __restrict__ xo) {
  constexpr int C4 = C / 4;
  int t = blockIdx.x * 256 + threadIdx.x;  // NP*C4
  int i = t / C4, q = t % C4;
  float4 base = *(const float4*)&bz[(size_t)i * (2 * C) + q * 4];
  float4 scl = *(const float4*)&s[q * 4];
  float4 bia = *(const float4*)&b[q * 4];
  float ax = 0.f, ay = 0.f, az = 0.f, aw = 0.f;
  const int* ip = idx + i * 16;
#pragma unroll
  for (int n = 0; n < 16; ++n) {
    int j = ip[n];
    float4 z = *(const float4*)&bz[(size_t)j * (2 * C) + C + q * 4];
    ax = fmaxf(ax, (base.x + z.x) * scl.x + bia.x);
    ay = fmaxf(ay, (base.y + z.y) * scl.y + bia.y);
    az = fmaxf(az, (base.z + z.z) * scl.z + bia.z);
    aw = fmaxf(aw, (base.w + z.w) * scl.w + bia.w);
  }
  us4 o;
  o[0] = f2h(ax); o[1] = f2h(ay); o[2] = f2h(az); o[3] = f2h(aw);
  *(us4*)&xo[(size_t)i * C + q * 4] = o;
}

// ---------------- attention ----------------
// q fp32 (NP x C), kv fp16 (NP x 2C): cols [0,C)=k, [C,2C)=v.
template <int C>
__global__ __launch_bounds__(256) void attn_logits_k(const float* __restrict__ qf,
                                                     const unsigned short* __restrict__ kvb,
                                                     const int* __restrict__ idx,
                                                     float* __restrict__ aout,
                                                     float scale) {
  int i = blockIdx.x * 4 + (threadIdx.x >> 6);
  int lane = threadIdx.x & 63;
  constexpr int G = C / 256;
  float4 qv[G];
#pragma unroll
  for (int g = 0; g < G; ++g)
    qv[g] = *(const float4*)&qf[(size_t)i * C + 4 * lane + 256 * g];
  float lg[16];
#pragma unroll
  for (int n = 0; n < 16; ++n) {
    int j = idx[i * 16 + n];
    const unsigned short* kr = kvb + (size_t)j * (2 * C);
    float ssum = 0.f;
#pragma unroll
    for (int g = 0; g < G; ++g) {
      us4 kk = *(const us4*)&kr[4 * lane + 256 * g];
      ssum += qv[g].x * h2f(kk[0]) + qv[g].y * h2f(kk[1]) +
              qv[g].z * h2f(kk[2]) + qv[g].w * h2f(kk[3]);
    }
    lg[n] = ssum;
  }
#pragma unroll
  for (int n = 0; n < 16; ++n) {
    float vv = lg[n];
    for (int o = 32; o >= 1; o >>= 1) vv += __shfl_xor(vv, o);
    lg[n] = vv * scale;
  }
  float m = lg[0];
#pragma unroll
  for (int n = 1; n < 16; ++n) m = fmaxf(m, lg[n]);
  float ssum = 0.f;
#pragma unroll
  for (int n = 0; n < 16; ++n) { lg[n] = __expf(lg[n] - m); ssum += lg[n]; }
  float inv = 1.f / ssum;
  if (lane == 0) {
#pragma unroll
    for (int n = 0; n < 16; ++n) aout[i * 16 + n] = lg[n] * inv;
  }
}

template <int C>
__global__ __launch_bounds__(256) void attn_apply_k(const unsigned short* __restrict__ kvb,
                                                    const int* __restrict__ idx,
                                                    const float* __restrict__ awp,
                                                    const float* __restrict__ s,
                                                    const float* __restrict__ b,
                                                    unsigned short* __restrict__ xo) {
  constexpr int C4 = C / 4;
  int t = blockIdx.x * 256 + threadIdx.x;  // NP*C4
  int i = t / C4, q = t % C4;
  float ax = 0.f, ay = 0.f, az = 0.f, aw2 = 0.f;
  const int* ip = idx + i * 16;
  const float* ap = awp + i * 16;
#pragma unroll
  for (int n = 0; n < 16; ++n) {
    int j = ip[n];
    float w = ap[n];
    us4 v4 = *(const us4*)&kvb[(size_t)j * (2 * C) + C + 4 * q];
    ax += w * h2f(v4[0]); ay += w * h2f(v4[1]);
    az += w * h2f(v4[2]); aw2 += w * h2f(v4[3]);
  }
  float4 scl = *(const float4*)&s[q * 4];
  float4 bia = *(const float4*)&b[q * 4];
  ax = fmaxf(ax * scl.x + bia.x, 0.f);
  ay = fmaxf(ay * scl.y + bia.y, 0.f);
  az = fmaxf(az * scl.z + bia.z, 0.f);
  aw2 = fmaxf(aw2 * scl.w + bia.w, 0.f);
  us4 o;
  o[0] = f2h(ax); o[1] = f2h(ay); o[2] = f2h(az); o[3] = f2h(aw2);
  *(us4*)&xo[(size_t)i * C + q * 4] = o;
}

// ---------------- down stage ----------------
__global__ __launch_bounds__(256) void down_gm_k(const float* __restrict__ vbuf,
                                                 const float4* __restrict__ soa,
                                                 const float* __restrict__ Wtd,
                                                 const int* __restrict__ idx,
                                                 const float* __restrict__ sd,
                                                 const float* __restrict__ bd,
                                                 unsigned short* __restrict__ xd) {
  int t = blockIdx.x * 256 + threadIdx.x;  // 2048*128
  int i = t >> 7, q = t & 127;
  int qi = 4 * i;
  float4 qp = soa[qi];
  float4 w0 = *(const float4*)&Wtd[q * 4];
  float4 w1 = *(const float4*)&Wtd[512 + q * 4];
  float4 w2 = *(const float4*)&Wtd[1024 + q * 4];
  float px = qp.x * w0.x + qp.y * w1.x + qp.z * w2.x;
  float py = qp.x * w0.y + qp.y * w1.y + qp.z * w2.y;
  float pz = qp.x * w0.z + qp.y * w1.z + qp.z * w2.z;
  float pw2 = qp.x * w0.w + qp.y * w1.w + qp.z * w2.w;
  float4 scl = *(const float4*)&sd[q * 4];
  float4 bia = *(const float4*)&bd[q * 4];
  float ax = 0.f, ay = 0.f, az = 0.f, aw = 0.f;
  const int* ip = idx + qi * 16;
#pragma unroll
  for (int n = 0; n < 16; ++n) {
    int j = ip[n];
    float4 v = *(const float4*)&vbuf[(size_t)j * 512 + q * 4];
    ax = fmaxf(ax, (v.x - px) * scl.x + bia.x);
    ay = fmaxf(ay, (v.y - py) * scl.y + bia.y);
    az = fmaxf(az, (v.z - pz) * scl.z + bia.z);
    aw = fmaxf(aw, (v.w - pw2) * scl.w + bia.w);
  }
  us4 o;
  o[0] = f2h(ax); o[1] = f2h(ay); o[2] = f2h(az); o[3] = f2h(aw);
  *(us4*)&xd[(size_t)i * 512 + q * 4] = o;
}

__global__ __launch_bounds__(512) void colsum_k(const unsigned short* __restrict__ xd,
                                                float* __restrict__ part) {
  int b = blockIdx.x;           // 16
  int c = threadIdx.x;          // 512
  float s = 0.f;
  for (int r = b * 128; r < (b + 1) * 128; ++r) s += h2f(xd[(size_t)r * 512 + c]);
  part[b * 512 + c] = s;
}

__global__ __launch_bounds__(256) void gterm_k(const float* __restrict__ part,
                                               const float* __restrict__ Wu2,
                                               const float* __restrict__ su2,
                                               const float* __restrict__ bu2,
                                               float* __restrict__ gterm) {
  __shared__ float gm[512];
  int tid = threadIdx.x;
  for (int c = tid; c < 512; c += 256) {
    float s = 0.f;
#pragma unroll
    for (int b = 0; b < 16; ++b) s += part[b * 512 + c];
    gm[c] = s * (1.f / 2048.f);
  }
  __syncthreads();
  float s = 0.f;
  for (int c = 0; c < 512; ++c) s += gm[c] * Wu2[c * 256 + tid];
  gterm[tid] = s * su2[tid] + bu2[tid];
}

// ---------------- MFMA GEMM (fp16 1-term) ----------------
// C = A @ W^T; A fp16 plane (M x K), W^T fp16 (N x K). 128x128 tile, BK=32.
// MODE 0: fp32 out. MODE 1: += p@Wtd[0:3], fp32 out. MODE 2: relu(acc*s1+b1+s2)
// fp16 out. MODE 3: relu((acc+b1)*s1+s2) fp32 out. MODE 4: q fp32 + kv fp16.
#define LDSROW 80
template <int MODE>
__global__ __launch_bounds__(256) void gemm_mfma(
    const unsigned short* __restrict__ A,
    const unsigned short* __restrict__ B,
    float* __restrict__ Cf, unsigned short* __restrict__ Ch,
    int M, int N, int K,
    const float4* __restrict__ soaD, const float* __restrict__ wtd,
    const float* __restrict__ s1, const float* __restrict__ b1,
    const float* __restrict__ s2, int Cq, unsigned short* __restrict__ kvb) {
  __shared__ __align__(16) char smem[2 * 128 * LDSROW];
  char* A_s = smem;
  char* B_s = smem + 128 * LDSROW;

  const int tid = threadIdx.x;
  const int lane = tid & 63;
  const int wid = tid >> 6;
  const int wm = wid >> 1, wn = wid & 1;
  const int bm = blockIdx.y * 128, bn = blockIdx.x * 128;
  const int r16 = lane & 15, kb = lane >> 4;

  f32x4 acc[4][4];
#pragma unroll
  for (int a = 0; a < 4; ++a)
#pragma unroll
    for (int b = 0; b < 4; ++b) acc[a][b] = (f32x4)(0.f);

  for (int k0 = 0; k0 < K; k0 += 32) {
    __syncthreads();
#pragma unroll
    for (int qq = 0; qq < 2; ++qq) {
      int idx8 = qq * 256 + tid;
      int row = idx8 >> 2, sq = idx8 & 3;
      size_t goA = (size_t)(bm + row) * K + k0 + sq * 8;
      size_t goB = (size_t)(bn + row) * K + k0 + sq * 8;
      ushort8 a_v = *(const ushort8*)&A[goA];
      ushort8 b_v = *(const ushort8*)&B[goB];
      *(ushort8*)(A_s + row * LDSROW + sq * 16) = a_v;
      *(ushort8*)(B_s + row * LDSROW + sq * 16) = b_v;
    }
    __syncthreads();

    half8 ah[4];
#pragma unroll
    for (int mi = 0; mi < 4; ++mi) {
      int off = (wm * 64 + mi * 16 + r16) * LDSROW + kb * 16;
      ah[mi] = *(const half8*)(A_s + off);
    }
#pragma unroll
    for (int ni = 0; ni < 4; ++ni) {
      int off = (wn * 64 + ni * 16 + r16) * LDSROW + kb * 16;
      half8 bh = *(const half8*)(B_s + off);
#pragma unroll
      for (int mi = 0; mi < 4; ++mi) {
        acc[mi][ni] = __builtin_amdgcn_mfma_f32_16x16x32_f16(ah[mi], bh, acc[mi][ni], 0, 0, 0);
      }
    }
  }

#pragma unroll
  for (int mi = 0; mi < 4; ++mi) {
#pragma unroll
    for (int ni = 0; ni < 4; ++ni) {
      int r0 = bm + wm * 64 + mi * 16 + (lane >> 4) * 4;
      int cc = bn + wn * 64 + ni * 16 + (lane & 15);
      float w0 = 0.f, w1 = 0.f, w2 = 0.f;
      if (MODE == 1) { w0 = wtd[cc]; w1 = wtd[512 + cc]; w2 = wtd[1024 + cc]; }
#pragma unroll
      for (int j = 0; j < 4; ++j) {
        float vv = acc[mi][ni][j];
        int row = r0 + j;
        if (MODE == 1) {
          float4 P = soaD[row];
          vv += P.x * w0 + P.y * w1 + P.z * w2;
        }
        if (MODE == 2) vv = fmaxf(vv * s1[cc] + b1[cc] + s2[cc], 0.f);
        if (MODE == 3) vv = fmaxf((vv + b1[cc]) * s1[cc] + s2[cc], 0.f);
        if (MODE == 2) {
          Ch[(size_t)row * N + cc] = f2h(vv);
        } else if (MODE == 4) {
          if (cc < Cq) Cf[(size_t)row * Cq + cc] = vv;
          else kvb[(size_t)row * (2 * Cq) + (cc - Cq)] = f2h(vv);
        } else {
          Cf[(size_t)row * N + cc] = vv;
        }
      }
    }
  }
}

// ---------------- final ----------------
__global__ __launch_bounds__(256) void out_k(const float* __restrict__ h,
                                             const float* __restrict__ Wc2,
                                             const float* __restrict__ bc2,
                                             float* __restrict__ out) {
  int t = blockIdx.x * 256 + threadIdx.x;  // 49152
  int pair = t >> 2, kq = t & 3;           // pair < 12288
  int i = pair / 6, o = pair % 6;
  float s = 0.f;
#pragma unroll 8
  for (int m = kq * 32; m < kq * 32 + 32; ++m) s += h[i * 128 + m] * Wc2[m * 6 + o];
  s += __shfl_xor(s, 1);
  s += __shfl_xor(s, 2);
  if (kq == 0) out[pair] = s + bc2[o];
}

extern "C" void kernel_launch(void* const* d_in, const int* in_sizes, int n_in,
                              void* d_out, int out_size, void* d_ws, size_t ws_size,
                              hipStream_t stream) {
  const float* pts = (const float*)d_in[0];
  const float* We1 = (const float*)d_in[1];
  const float* se1 = (const float*)d_in[2];
  const float* be1 = (const float*)d_in[3];
  const float* We2 = (const float*)d_in[4];
  const float* se2 = (const float*)d_in[5];
  const float* be2 = (const float*)d_in[6];
  const float* Wq1 = (const float*)d_in[7];
  const float* Wk1 = (const float*)d_in[8];
  const float* Wv1 = (const float*)d_in[9];
  const float* sa1 = (const float*)d_in[10];
  const float* ba1 = (const float*)d_in[11];
  const float* Wq2 = (const float*)d_in[12];
  const float* Wk2 = (const float*)d_in[13];
  const float* Wv2 = (const float*)d_in[14];
  const float* sa2 = (const float*)d_in[15];
  const float* ba2 = (const float*)d_in[16];
  const float* Wtd = (const float*)d_in[17];
  const float* sd  = (const float*)d_in[18];
  const float* bd  = (const float*)d_in[19];
  const float* Wu1 = (const float*)d_in[20];
  const float* su1 = (const float*)d_in[21];
  const float* bu1 = (const float*)d_in[22];
  const float* Wu2 = (const float*)d_in[23];
  const float* su2 = (const float*)d_in[24];
  const float* bu2 = (const float*)d_in[25];
  const float* Wc1 = (const float*)d_in[26];
  const float* bc1 = (const float*)d_in[27];
  const float* sc  = (const float*)d_in[28];
  const float* bc  = (const float*)d_in[29];
  const float* Wc2 = (const float*)d_in[30];
  const float* bc2 = (const float*)d_in[31];

  float* ws = (float*)d_ws;
  if (ws_size < (size_t)16703744 * 4) return;  // ~66.8 MB (layout as round 7)
  float* soa   = ws;                      // 32768
  int*   idx   = (int*)(ws + 32768);      // 131072 ints
  float* attw  = ws + 163840;             // 131072
  float* gpart = ws + 294912;             // 8192
  float* gterm = ws + 303104;             // 256
  unsigned short* wthi = (unsigned short*)(ws + 303360);   // 933888 ush
  unsigned short* x1   = (unsigned short*)(ws + 1237248);  // 524288 ush
  unsigned short* x2   = (unsigned short*)(ws + 1499392);  // 1048576 ush
  unsigned short* x3   = (unsigned short*)(ws + 2023680);  // 2097152 ush
  unsigned short* x4   = (unsigned short*)(ws + 3072256);  // 4194304 ush
  unsigned short* xd   = (unsigned short*)(ws + 5169408);  // 1048576 ush
  unsigned short* xu   = (unsigned short*)(ws + 5693696);  // 524288 ush
  float* bufP  = ws + 5955840;            // 2097152 f (bz1/bz2)
  float* qf    = ws + 8052992;            // 4194304 f (q planes / vbuf)
  unsigned short* kvb = (unsigned short*)(ws + 12247296);  // 8388608 ush
  float* hbuf  = ws + 16441600;           // 262144 f

  prep_points_k<<<32, 256, 0, stream>>>(pts, (float4*)soa);
  wsplit_k<<<3648, 256, 0, stream>>>(We2, Wq1, Wk1, Wv1, Wq2, Wk2, Wv2, Wtd, Wu1, Wc1, wthi);
  knn_k<<<1024, 512, 0, stream>>>((const float4*)soa, idx);

  // edge conv 1
  proj1_k<<<4096, 256, 0, stream>>>((const float4*)soa, We1, bufP);
  ec_gm_k<64><<<512, 256, 0, stream>>>(bufP, idx, se1, be1, x1);

  // edge conv 2
  gemm_mfma<0><<<dim3(2, 64), 256, 0, stream>>>(x1, wthi,
      bufP, nullptr, NP, 256, 64, nullptr, nullptr, nullptr, nullptr, nullptr, 0, nullptr);
  ec_gm_k<128><<<1024, 256, 0, stream>>>(bufP, idx, se2, be2, x2);

  // attn 1
  gemm_mfma<4><<<dim3(6, 64), 256, 0, stream>>>(x2, wthi + 16384,
      qf, nullptr, NP, 768, 128, nullptr, nullptr, nullptr, nullptr, nullptr, 256, kvb);
  attn_logits_k<256><<<2048, 256, 0, stream>>>(qf, kvb, idx, attw, 0.0625f);
  attn_apply_k<256><<<2048, 256, 0, stream>>>(kvb, idx, attw, sa1, ba1, x3);

  // attn 2
  gemm_mfma<4><<<dim3(12, 64), 256, 0, stream>>>(x3, wthi + 114688,
      qf, nullptr, NP, 1536, 256, nullptr, nullptr, nullptr, nullptr, nullptr, 512, kvb);
  attn_logits_k<512><<<2048, 256, 0, stream>>>(qf, kvb, idx, attw, 0.04419417382415922f);
  attn_apply_k<512><<<4096, 256, 0, stream>>>(kvb, idx, attw, sa2, ba2, x4);

  // down
  gemm_mfma<1><<<dim3(4, 64), 256, 0, stream>>>(x4, wthi + 507904,
      qf, nullptr, NP, 512, 512, (const float4*)soa, Wtd, nullptr, nullptr, nullptr, 0, nullptr);
  down_gm_k<<<1024, 256, 0, stream>>>(qf, (const float4*)soa, Wtd, idx, sd, bd, xd);

  // global mean term
  colsum_k<<<16, 512, 0, stream>>>(xd, gpart);
  gterm_k<<<1, 256, 0, stream>>>(gpart, Wu2, su2, bu2, gterm);

  // xu
  gemm_mfma<2><<<dim3(2, 16), 256, 0, stream>>>(xd, wthi + 770048,
      nullptr, xu, NDOWN, 256, 512, nullptr, nullptr, su1, bu1, gterm, 0, nullptr);
  // h
  gemm_mfma<3><<<dim3(1, 16), 256, 0, stream>>>(xu, wthi + 901120,
      hbuf, nullptr, NDOWN, 128, 256, nullptr, nullptr, sc, bc1, bc, 0, nullptr);
  // out
  out_k<<<192, 256, 0, stream>>>(hbuf, Wc2, bc2, (float*)d_out);
}